// Round 1
// baseline (729.459 us; speedup 1.0000x reference)
//
#include <hip/hip_runtime.h>
#include <hip/hip_bf16.h>
#include <stdint.h>

#define S_LEN 512
#define BATCH 512
#define HID   128
#define G3    384
#define EMB   50
#define VOC   50000

typedef __attribute__((ext_vector_type(8))) short short8;
typedef __attribute__((ext_vector_type(4))) float float4v;
typedef __attribute__((ext_vector_type(4))) unsigned short ushort4v;

__device__ inline unsigned short f2bf(float f) {
  union { float f; uint32_t u; } v; v.f = f;
  uint32_t u = v.u;
  u += 0x7fffu + ((u >> 16) & 1u);   // RNE
  return (unsigned short)(u >> 16);
}
__device__ inline float bf2f(unsigned short h) {
  union { uint32_t u; float f; } v; v.u = ((uint32_t)h) << 16;
  return v.f;
}
__device__ inline float fast_sig(float x) {
  return __builtin_amdgcn_rcpf(1.f + __expf(-x));
}

// ---------------------------------------------------------------------------
// Kernel A: gxv[v][g] = b_ih[g] + sum_e W_ih[g][e] * emb[v][e]   (bf16 table)
// ---------------------------------------------------------------------------
__global__ __launch_bounds__(384) void build_gxv(
    const float* __restrict__ emb, const float* __restrict__ W_ih,
    const float* __restrict__ b_ih, unsigned short* __restrict__ gxv) {
  __shared__ float se[128 * EMB];
  const int g  = threadIdx.x;          // 0..383 == gate row
  const int v0 = blockIdx.x * 128;
  const int cnt = min(128, VOC - v0);

  float wih[EMB];
#pragma unroll
  for (int e = 0; e < EMB; ++e) wih[e] = W_ih[g * EMB + e];
  const float bias = b_ih[g];

  for (int idx = threadIdx.x; idx < cnt * EMB; idx += 384)
    se[idx] = emb[(size_t)v0 * EMB + idx];
  __syncthreads();

  for (int v = 0; v < cnt; ++v) {
    float acc = bias;
#pragma unroll
    for (int e = 0; e < EMB; ++e) acc += wih[e] * se[v * EMB + e];
    gxv[(size_t)(v0 + v) * G3 + g] = f2bf(acc);
  }
}

// ---------------------------------------------------------------------------
// Kernel B: persistent GRU recurrence. 64 blocks = 2 GRUs x 32 batch-chunks.
// Block: 512 threads (8 waves). Wave w owns hidden units j in [16w,16w+16):
//   A-fragments (resident): W_hh rows {j, 128+j, 256+j} x K=128, bf16.
// Per step: gh^T = W_hh * h^T via 12 mfma_f32_16x16x32_bf16 per wave;
// gates elementwise in C-layout; h carried fp32 in regs; bf16 h^T copy via
// double-buffered LDS laid out in exact B-fragment order (1 barrier/step).
// ---------------------------------------------------------------------------
__global__ __launch_bounds__(512) void gru_kernel(
    const int* __restrict__ x1, const int* __restrict__ x2,
    const unsigned short* __restrict__ gxv, const float* __restrict__ W_hh,
    const float* __restrict__ b_hh, float* __restrict__ fcin) {
  const int bid   = blockIdx.x;
  const int gru   = bid >> 5;
  const int chunk = bid & 31;
  const int* xs   = gru ? x2 : x1;

  const int tid = threadIdx.x;
  const int w  = tid >> 6;        // wave 0..7
  const int L  = tid & 63;        // lane
  const int q  = L >> 4;          // quad 0..3
  const int ln = L & 15;          // n (batch within chunk) / m-in-tile
  const int jb = w * 16;
  const int j0 = jb + q * 4;      // this lane's 4 hidden units j0..j0+3
  const int ng = chunk * 16 + ln; // global batch index

  __shared__ __align__(16) unsigned short hbuf[2][2048]; // 2 x 4KB h^T B-frag buffers

  // --- resident A fragments: A[m = lane&15][k = quad*8 + i] per 16x16x32 ---
  short8 afrag[3][4];
#pragma unroll
  for (int t = 0; t < 3; ++t) {
    const float* wr = W_hh + (size_t)(t * 128 + jb + ln) * HID;
#pragma unroll
    for (int kf = 0; kf < 4; ++kf) {
      const int k0 = kf * 32 + q * 8;
      short8 a;
#pragma unroll
      for (int i = 0; i < 8; ++i) a[i] = (short)f2bf(wr[k0 + i]);
      afrag[t][kf] = a;
    }
  }

  float bh[3][4];
#pragma unroll
  for (int t = 0; t < 3; ++t)
#pragma unroll
    for (int r = 0; r < 4; ++r) bh[t][r] = b_hh[t * 128 + j0 + r];

  // zero both h buffers (h0 = 0)
  for (int idx = tid; idx < 4096; idx += 512) ((unsigned short*)hbuf)[idx] = 0;

  float h[4] = {0.f, 0.f, 0.f, 0.f};

  // gx prefetch: token(s) two ahead, gx one ahead
  const int tok0 = xs[ng];
  ushort4v gxc[3], gxn[3];
#pragma unroll
  for (int t = 0; t < 3; ++t)
    gxc[t] = *(const ushort4v*)(gxv + (size_t)tok0 * G3 + t * 128 + j0);
  int tok1 = xs[BATCH + ng];

  // h' write offset (B-fragment order): frag kf=j>>5, sublane q_b=(j>>3)&3, i=j&7
  const int kfw = j0 >> 5, qb = (j0 >> 3) & 3, i0 = j0 & 7;
  const int wofs = (kfw * 64 + qb * 16 + ln) * 8 + i0;

  __syncthreads();

  for (int s = 0; s < S_LEN; ++s) {
    // issue next-step gx gather + token load (independent of recurrence)
    if (s + 1 < S_LEN) {
#pragma unroll
      for (int t = 0; t < 3; ++t)
        gxn[t] = *(const ushort4v*)(gxv + (size_t)tok1 * G3 + t * 128 + j0);
    }
    const int tok2 = (s + 2 < S_LEN) ? xs[(s + 2) * BATCH + ng] : 0;

    // B fragments: h^T, B[k = quad*8+i][n = lane&15], pre-swizzled in LDS
    const unsigned short* rb = hbuf[s & 1];
    short8 bfrag[4];
#pragma unroll
    for (int kf = 0; kf < 4; ++kf)
      bfrag[kf] = *(const short8*)(rb + (kf * 64 + L) * 8);

    float4v acc[3];
#pragma unroll
    for (int t = 0; t < 3; ++t) {
      float4v a = {0.f, 0.f, 0.f, 0.f};
#pragma unroll
      for (int kf = 0; kf < 4; ++kf)
        a = __builtin_amdgcn_mfma_f32_16x16x32_bf16(afrag[t][kf], bfrag[kf], a, 0, 0, 0);
      acc[t] = a;
    }

    // gates: lane holds (j0+r, ng) for r=0..3; C-layout row = quad*4+reg
    unsigned short hw[4];
#pragma unroll
    for (int r = 0; r < 4; ++r) {
      const float gr  = bf2f(gxc[0][r]) + acc[0][r] + bh[0][r];
      const float gz  = bf2f(gxc[1][r]) + acc[1][r] + bh[1][r];
      const float ghn = acc[2][r] + bh[2][r];
      const float rg  = fast_sig(gr);
      const float zg  = fast_sig(gz);
      const float pre = bf2f(gxc[2][r]) + rg * ghn;
      const float nn  = 2.f * fast_sig(2.f * pre) - 1.f;  // tanh
      h[r] = (1.f - zg) * nn + zg * h[r];
      hw[r] = f2bf(h[r]);
    }

    ushort4v hv4 = {hw[0], hw[1], hw[2], hw[3]};
    *(ushort4v*)(hbuf[(s + 1) & 1] + wofs) = hv4;
    __syncthreads();

#pragma unroll
    for (int t = 0; t < 3; ++t) gxc[t] = gxn[t];
    tok1 = tok2;
  }

  // final h -> fcin[b][gru*128 + j]
  float4v hv = {h[0], h[1], h[2], h[3]};
  *(float4v*)(fcin + (size_t)ng * 256 + gru * 128 + j0) = hv;
}

// ---------------------------------------------------------------------------
// Kernel C: out[b] = sigmoid(b2 + W2 . relu(b1 + W1 . fcin[b]))
// ---------------------------------------------------------------------------
__global__ __launch_bounds__(128) void head_kernel(
    const float* __restrict__ fcin, const float* __restrict__ W1,
    const float* __restrict__ b1, const float* __restrict__ W2,
    const float* __restrict__ b2, float* __restrict__ out) {
  __shared__ float fc[256];
  __shared__ float part[2];
  const int b = blockIdx.x, t = threadIdx.x;
  fc[t]       = fcin[(size_t)b * 256 + t];
  fc[t + 128] = fcin[(size_t)b * 256 + t + 128];
  __syncthreads();

  float acc = b1[t];
#pragma unroll 8
  for (int k = 0; k < 256; ++k) acc += W1[t * 256 + k] * fc[k];
  const float hid = fmaxf(acc, 0.f);

  float v = hid * W2[t];
#pragma unroll
  for (int o = 32; o > 0; o >>= 1) v += __shfl_xor(v, o, 64);
  if ((t & 63) == 0) part[t >> 6] = v;
  __syncthreads();
  if (t == 0) {
    const float s = part[0] + part[1] + b2[0];
    out[b] = fast_sig(s);
  }
}

// ---------------------------------------------------------------------------
extern "C" void kernel_launch(void* const* d_in, const int* in_sizes, int n_in,
                              void* d_out, int out_size, void* d_ws, size_t ws_size,
                              hipStream_t stream) {
  const int*   x1   = (const int*)d_in[0];
  const int*   x2   = (const int*)d_in[1];
  const float* emb  = (const float*)d_in[2];
  const float* W_ih = (const float*)d_in[3];
  const float* W_hh = (const float*)d_in[4];
  const float* b_ih = (const float*)d_in[5];
  const float* b_hh = (const float*)d_in[6];
  const float* W1   = (const float*)d_in[7];
  const float* b1   = (const float*)d_in[8];
  const float* W2   = (const float*)d_in[9];
  const float* b2   = (const float*)d_in[10];
  float* out = (float*)d_out;

  unsigned short* gxv = (unsigned short*)d_ws;                  // 50000*384*2 = 38.4 MB
  float* fcin = (float*)((char*)d_ws + (size_t)VOC * G3 * 2);   // 512*256*4 = 512 KB

  build_gxv<<<(VOC + 127) / 128, 384, 0, stream>>>(emb, W_ih, b_ih, gxv);
  gru_kernel<<<64, 512, 0, stream>>>(x1, x2, gxv, W_hh, b_hh, fcin);
  head_kernel<<<512, 128, 0, stream>>>(fcin, W1, b1, W2, b2, out);
}

// Round 2
// 728.347 us; speedup vs baseline: 1.0015x; 1.0015x over previous
//
#include <hip/hip_runtime.h>
#include <hip/hip_bf16.h>
#include <stdint.h>

#define S_LEN 512
#define BATCH 512
#define HID   128
#define G3    384
#define EMB   50
#define VOC   50000

typedef __attribute__((ext_vector_type(8))) short short8;
typedef __attribute__((ext_vector_type(4))) float float4v;
typedef __attribute__((ext_vector_type(4))) unsigned short ushort4v;
typedef __attribute__((ext_vector_type(2))) uint32_t uint2v;

__device__ inline unsigned short f2bf(float f) {
  union { float f; uint32_t u; } v; v.f = f;
  uint32_t u = v.u;
  u += 0x7fffu + ((u >> 16) & 1u);   // RNE
  return (unsigned short)(u >> 16);
}
__device__ inline float bf2f(unsigned short h) {
  union { uint32_t u; float f; } v; v.u = ((uint32_t)h) << 16;
  return v.f;
}
__device__ inline uint32_t fbits(float f) {
  union { float f; uint32_t u; } v; v.f = f; return v.u;
}
__device__ inline float fast_sig(float x) {
  return __builtin_amdgcn_rcpf(1.f + __expf(-x));
}

// ---------------------------------------------------------------------------
// Kernel A: gxv[v][g] = b_ih[g] + (g<256 ? b_hh[g] : 0) + sum_e W_ih[g][e]*emb[v][e]
// (b_hr, b_hz folded in; b_hn cannot be — it is scaled by r inside the n-gate)
// ---------------------------------------------------------------------------
__global__ __launch_bounds__(384) void build_gxv(
    const float* __restrict__ emb, const float* __restrict__ W_ih,
    const float* __restrict__ b_ih, const float* __restrict__ b_hh,
    unsigned short* __restrict__ gxv) {
  __shared__ float se[128 * EMB];
  const int g  = threadIdx.x;          // 0..383 == gate row
  const int v0 = blockIdx.x * 128;
  const int cnt = min(128, VOC - v0);

  float wih[EMB];
#pragma unroll
  for (int e = 0; e < EMB; ++e) wih[e] = W_ih[g * EMB + e];
  const float bias = b_ih[g] + (g < 256 ? b_hh[g] : 0.f);

  for (int idx = threadIdx.x; idx < cnt * EMB; idx += 384)
    se[idx] = emb[(size_t)v0 * EMB + idx];
  __syncthreads();

  for (int v = 0; v < cnt; ++v) {
    float acc = bias;
#pragma unroll
    for (int e = 0; e < EMB; ++e) acc += wih[e] * se[v * EMB + e];
    gxv[(size_t)(v0 + v) * G3 + g] = f2bf(acc);
  }
}

// ---------------------------------------------------------------------------
// Kernel B: persistent GRU recurrence. 64 blocks = 2 GRUs x 32 batch-chunks.
// Block: 512 threads (8 waves). Wave w owns hidden units j in [16w,16w+16):
//   A-fragments (resident): W_hh rows {j, 128+j, 256+j} x K=128, bf16.
// Per step: gh^T = W_hh * h^T via 12 mfma_f32_16x16x32_bf16 per wave;
// gates elementwise in C-layout; h carried fp32 in regs; bf16 h^T copy via
// double-buffered LDS in exact B-fragment order.
// KEY: the per-step barrier waits lgkmcnt ONLY (inline asm) — global gx
// prefetch loads stay in flight across the barrier (AITER-style), hiding
// the ~900-cyc L2-miss gather latency behind the full step body.
// ---------------------------------------------------------------------------
__global__ __launch_bounds__(512) void gru_kernel(
    const int* __restrict__ x1, const int* __restrict__ x2,
    const unsigned short* __restrict__ gxv, const float* __restrict__ W_hh,
    const float* __restrict__ b_hh, float* __restrict__ fcin) {
  const int bid   = blockIdx.x;
  const int gru   = bid >> 5;
  const int chunk = bid & 31;
  const int* xs   = gru ? x2 : x1;

  const int tid = threadIdx.x;
  const int w  = tid >> 6;        // wave 0..7
  const int L  = tid & 63;        // lane
  const int q  = L >> 4;          // quad 0..3
  const int ln = L & 15;          // n (batch within chunk) / m-in-tile
  const int jb = w * 16;
  const int j0 = jb + q * 4;      // this lane's 4 hidden units j0..j0+3
  const int ng = chunk * 16 + ln; // global batch index

  __shared__ __align__(16) unsigned short hbuf[2][2048]; // 2 x 4KB h^T B-frag buffers

  // --- resident A fragments: A[m = lane&15][k = quad*8 + i] per 16x16x32 ---
  short8 afrag[3][4];
#pragma unroll
  for (int t = 0; t < 3; ++t) {
    const float* wr = W_hh + (size_t)(t * 128 + jb + ln) * HID;
#pragma unroll
    for (int kf = 0; kf < 4; ++kf) {
      const int k0 = kf * 32 + q * 8;
      float4v f0 = *(const float4v*)(wr + k0);
      float4v f1 = *(const float4v*)(wr + k0 + 4);
      short8 a;
#pragma unroll
      for (int i = 0; i < 4; ++i) a[i] = (short)f2bf(f0[i]);
#pragma unroll
      for (int i = 0; i < 4; ++i) a[i + 4] = (short)f2bf(f1[i]);
      afrag[t][kf] = a;
    }
  }

  float bhn[4];
#pragma unroll
  for (int r = 0; r < 4; ++r) bhn[r] = b_hh[2 * 128 + j0 + r];

  // zero both h buffers (h0 = 0)
  for (int idx = tid; idx < 4096; idx += 512) ((unsigned short*)hbuf)[idx] = 0;

  float h[4] = {0.f, 0.f, 0.f, 0.f};

  // gx prefetch: token(s) two ahead, gx one ahead
  const int tok0 = xs[ng];
  ushort4v gxc[3], gxn[3];
  {
    const unsigned short* gp = gxv + (size_t)tok0 * G3 + j0;
    gxc[0] = *(const ushort4v*)(gp);
    gxc[1] = *(const ushort4v*)(gp + 128);
    gxc[2] = *(const ushort4v*)(gp + 256);
  }
  int tok1 = xs[BATCH + ng];

  // h' write offset (B-fragment order): frag kf=j>>5, sublane q_b=(j>>3)&3, i=j&7
  const int kfw = j0 >> 5, qb = (j0 >> 3) & 3, i0 = j0 & 7;
  const int wofs = (kfw * 64 + qb * 16 + ln) * 8 + i0;

  __syncthreads();

#pragma unroll 2
  for (int s = 0; s < S_LEN; ++s) {
    // issue next-step gx gather + token load (stays in flight across barrier)
    if (s + 1 < S_LEN) {
      const unsigned short* gp = gxv + (size_t)tok1 * G3 + j0;
      gxn[0] = *(const ushort4v*)(gp);
      gxn[1] = *(const ushort4v*)(gp + 128);
      gxn[2] = *(const ushort4v*)(gp + 256);
    }
    const int tok2 = (s + 2 < S_LEN) ? xs[(s + 2) * BATCH + ng] : 0;

    // B fragments: h^T, B[k = quad*8+i][n = lane&15], pre-swizzled in LDS
    const unsigned short* rb = hbuf[s & 1];
    short8 bfrag[4];
#pragma unroll
    for (int kf = 0; kf < 4; ++kf)
      bfrag[kf] = *(const short8*)(rb + (kf * 64 + L) * 8);

    float4v acc[3];
#pragma unroll
    for (int t = 0; t < 3; ++t) {
      float4v a = {0.f, 0.f, 0.f, 0.f};
#pragma unroll
      for (int kf = 0; kf < 4; ++kf)
        a = __builtin_amdgcn_mfma_f32_16x16x32_bf16(afrag[t][kf], bfrag[kf], a, 0, 0, 0);
      acc[t] = a;
    }

    // gates: lane holds (j0+r, ng) for r=0..3; C-layout row = quad*4+reg
#pragma unroll
    for (int r = 0; r < 4; ++r) {
      const float gr  = bf2f(gxc[0][r]) + acc[0][r];        // b_hr folded in gxv
      const float gz  = bf2f(gxc[1][r]) + acc[1][r];        // b_hz folded in gxv
      const float ghn = acc[2][r] + bhn[r];
      const float rg  = fast_sig(gr);
      const float zg  = fast_sig(gz);
      const float pre = bf2f(gxc[2][r]) + rg * ghn;
      const float nn  = 2.f * fast_sig(2.f * pre) - 1.f;    // tanh
      h[r] = zg * (h[r] - nn) + nn;
    }

    // pack 4 fp32 -> 4 bf16 (round-half-up) via 2x v_perm_b32
    const uint32_t p0 = __builtin_amdgcn_perm(fbits(h[1]) + 0x8000u,
                                              fbits(h[0]) + 0x8000u, 0x07060302u);
    const uint32_t p1 = __builtin_amdgcn_perm(fbits(h[3]) + 0x8000u,
                                              fbits(h[2]) + 0x8000u, 0x07060302u);
    uint2v hv; hv[0] = p0; hv[1] = p1;
    *(uint2v*)(hbuf[(s + 1) & 1] + wofs) = hv;

    // LDS-only barrier: do NOT drain vmcnt — gx prefetch stays in flight
    asm volatile("s_waitcnt lgkmcnt(0)\n\ts_barrier" ::: "memory");

#pragma unroll
    for (int t = 0; t < 3; ++t) gxc[t] = gxn[t];
    tok1 = tok2;
  }

  // final h -> fcin[b][gru*128 + j]
  float4v hv = {h[0], h[1], h[2], h[3]};
  *(float4v*)(fcin + (size_t)ng * 256 + gru * 128 + j0) = hv;
}

// ---------------------------------------------------------------------------
// Kernel C: out[b] = sigmoid(b2 + W2 . relu(b1 + W1 . fcin[b]))
// ---------------------------------------------------------------------------
__global__ __launch_bounds__(128) void head_kernel(
    const float* __restrict__ fcin, const float* __restrict__ W1,
    const float* __restrict__ b1, const float* __restrict__ W2,
    const float* __restrict__ b2, float* __restrict__ out) {
  __shared__ float fc[256];
  __shared__ float part[2];
  const int b = blockIdx.x, t = threadIdx.x;
  fc[t]       = fcin[(size_t)b * 256 + t];
  fc[t + 128] = fcin[(size_t)b * 256 + t + 128];
  __syncthreads();

  float acc = b1[t];
#pragma unroll 8
  for (int k = 0; k < 256; ++k) acc += W1[t * 256 + k] * fc[k];
  const float hid = fmaxf(acc, 0.f);

  float v = hid * W2[t];
#pragma unroll
  for (int o = 32; o > 0; o >>= 1) v += __shfl_xor(v, o, 64);
  if ((t & 63) == 0) part[t >> 6] = v;
  __syncthreads();
  if (t == 0) {
    const float s = part[0] + part[1] + b2[0];
    out[b] = fast_sig(s);
  }
}

// ---------------------------------------------------------------------------
extern "C" void kernel_launch(void* const* d_in, const int* in_sizes, int n_in,
                              void* d_out, int out_size, void* d_ws, size_t ws_size,
                              hipStream_t stream) {
  const int*   x1   = (const int*)d_in[0];
  const int*   x2   = (const int*)d_in[1];
  const float* emb  = (const float*)d_in[2];
  const float* W_ih = (const float*)d_in[3];
  const float* W_hh = (const float*)d_in[4];
  const float* b_ih = (const float*)d_in[5];
  const float* b_hh = (const float*)d_in[6];
  const float* W1   = (const float*)d_in[7];
  const float* b1   = (const float*)d_in[8];
  const float* W2   = (const float*)d_in[9];
  const float* b2   = (const float*)d_in[10];
  float* out = (float*)d_out;

  unsigned short* gxv = (unsigned short*)d_ws;                  // 50000*384*2 = 38.4 MB
  float* fcin = (float*)((char*)d_ws + (size_t)VOC * G3 * 2);   // 512*256*4 = 512 KB

  build_gxv<<<(VOC + 127) / 128, 384, 0, stream>>>(emb, W_ih, b_ih, b_hh, gxv);
  gru_kernel<<<64, 512, 0, stream>>>(x1, x2, gxv, W_hh, b_hh, fcin);
  head_kernel<<<512, 128, 0, stream>>>(fcin, W1, b1, W2, b2, out);
}

// Round 3
// 598.434 us; speedup vs baseline: 1.2189x; 1.2171x over previous
//
#include <hip/hip_runtime.h>
#include <hip/hip_bf16.h>
#include <stdint.h>

#define S_LEN 512
#define BATCH 512
#define HID   128
#define G3    384
#define EMB   50
#define VOC   50000

typedef __attribute__((ext_vector_type(8))) short short8;
typedef __attribute__((ext_vector_type(4))) float float4v;
typedef __attribute__((ext_vector_type(2))) float float2v;
typedef __attribute__((ext_vector_type(4))) unsigned short ushort4v;
typedef __attribute__((ext_vector_type(2))) uint32_t uint2v;

__device__ inline unsigned short f2bf(float f) {
  union { float f; uint32_t u; } v; v.f = f;
  uint32_t u = v.u;
  u += 0x7fffu + ((u >> 16) & 1u);   // RNE
  return (unsigned short)(u >> 16);
}
__device__ inline float bf2f(unsigned short h) {
  union { uint32_t u; float f; } v; v.u = ((uint32_t)h) << 16;
  return v.f;
}
__device__ inline uint32_t fbits(float f) {
  union { float f; uint32_t u; } v; v.f = f; return v.u;
}
__device__ inline float fast_sig(float x) {
  return __builtin_amdgcn_rcpf(1.f + __expf(-x));
}

// ---------------------------------------------------------------------------
// Kernel A: gxv[v][g] = b_ih[g] + (g<256 ? b_hh[g] : 0) + sum_e W_ih[g][e]*emb[v][e]
// v2: emb tile TRANSPOSED in LDS (seT[e][v]) so 4 vocab rows load as one
// ds_read_b128; 2 gate-rows per thread (wih resident in 100 VGPRs) -> 8 FMA
// per LDS instr (was 1). LDS-pipe instrs per thread: 1600 b128 vs 6400 b32.
// ---------------------------------------------------------------------------
__global__ __launch_bounds__(192) void build_gxv(
    const float* __restrict__ emb, const float* __restrict__ W_ih,
    const float* __restrict__ b_ih, const float* __restrict__ b_hh,
    unsigned short* __restrict__ gxv) {
  __shared__ float seT[EMB * 128];   // seT[e][v], 25.6 KB
  const int t  = threadIdx.x;        // 0..191
  const int g0 = t, g1 = t + 192;
  const int v0 = blockIdx.x * 128;
  const int cnt = min(128, VOC - v0);

  float w0[EMB], w1[EMB];
#pragma unroll
  for (int e = 0; e < EMB; ++e) w0[e] = W_ih[g0 * EMB + e];
#pragma unroll
  for (int e = 0; e < EMB; ++e) w1[e] = W_ih[g1 * EMB + e];
  const float b0 = b_ih[g0] + (g0 < 256 ? b_hh[g0] : 0.f);
  const float b1 = b_ih[g1] + (g1 < 256 ? b_hh[g1] : 0.f);

  for (int idx = t; idx < cnt * EMB; idx += 192) {
    const int v = idx / EMB, e = idx - v * EMB;
    seT[e * 128 + v] = emb[(size_t)(v0 + v) * EMB + e];
  }
  __syncthreads();

  for (int vt = 0; vt < 32; ++vt) {
    float4v a0 = {b0, b0, b0, b0}, a1 = {b1, b1, b1, b1};
#pragma unroll
    for (int e = 0; e < EMB; ++e) {
      const float4v sv = *(const float4v*)(seT + e * 128 + vt * 4);
      a0 += sv * w0[e];
      a1 += sv * w1[e];
    }
    const int vbase = vt * 4;
#pragma unroll
    for (int vv = 0; vv < 4; ++vv) {
      if (vbase + vv < cnt) {
        unsigned short* p = gxv + (size_t)(v0 + vbase + vv) * G3;
        p[g0] = f2bf(a0[vv]);
        p[g1] = f2bf(a1[vv]);
      }
    }
  }
}

// ---------------------------------------------------------------------------
// Kernel B: persistent GRU recurrence. 64 blocks = 2 GRUs x 32 batch-chunks.
// Block: 512 threads (8 waves). Wave w owns hidden units j in [16w,16w+16):
//   A-fragments (resident): W_hh rows {j, 128+j, 256+j} x K=128, bf16.
// Per step: gh^T = W_hh * h^T via 12 mfma_f32_16x16x32_bf16 per wave
// (2 independent 2-deep chains per gate); gates elementwise in C-layout with
// PACKED f32 math (v_pk_*); h carried fp32 in regs; bf16 h^T via
// double-buffered LDS in exact B-fragment order; lgkm-only barrier.
// ---------------------------------------------------------------------------
__global__ __launch_bounds__(512) void gru_kernel(
    const int* __restrict__ x1, const int* __restrict__ x2,
    const unsigned short* __restrict__ gxv, const float* __restrict__ W_hh,
    const float* __restrict__ b_hh, float* __restrict__ fcin) {
  const int bid   = blockIdx.x;
  const int gru   = bid >> 5;
  const int chunk = bid & 31;
  const int* xs   = gru ? x2 : x1;

  const int tid = threadIdx.x;
  const int w  = tid >> 6;        // wave 0..7
  const int L  = tid & 63;        // lane
  const int q  = L >> 4;          // quad 0..3
  const int ln = L & 15;          // n (batch within chunk) / m-in-tile
  const int jb = w * 16;
  const int j0 = jb + q * 4;      // this lane's 4 hidden units j0..j0+3
  const int ng = chunk * 16 + ln; // global batch index

  __shared__ __align__(16) unsigned short hbuf[2][2048]; // 2 x 4KB h^T B-frag buffers

  // --- resident A fragments: A[m = lane&15][k = quad*8 + i] per 16x16x32 ---
  short8 afrag[3][4];
#pragma unroll
  for (int t = 0; t < 3; ++t) {
    const float* wr = W_hh + (size_t)(t * 128 + jb + ln) * HID;
#pragma unroll
    for (int kf = 0; kf < 4; ++kf) {
      const int k0 = kf * 32 + q * 8;
      float4v f0 = *(const float4v*)(wr + k0);
      float4v f1 = *(const float4v*)(wr + k0 + 4);
      short8 a;
#pragma unroll
      for (int i = 0; i < 4; ++i) a[i] = (short)f2bf(f0[i]);
#pragma unroll
      for (int i = 0; i < 4; ++i) a[i + 4] = (short)f2bf(f1[i]);
      afrag[t][kf] = a;
    }
  }

  float2v bhn2[2];
#pragma unroll
  for (int p = 0; p < 2; ++p) {
    bhn2[p].x = b_hh[2 * 128 + j0 + 2 * p];
    bhn2[p].y = b_hh[2 * 128 + j0 + 2 * p + 1];
  }

  // zero both h buffers (h0 = 0)
  for (int idx = tid; idx < 4096; idx += 512) ((unsigned short*)hbuf)[idx] = 0;

  float2v h2[2];
  h2[0] = (float2v){0.f, 0.f};
  h2[1] = (float2v){0.f, 0.f};

  // gx prefetch: token(s) two ahead, gx one ahead
  const int tok0 = xs[ng];
  ushort4v gxc[3], gxn[3];
  {
    const unsigned short* gp = gxv + (size_t)tok0 * G3 + j0;
    gxc[0] = *(const ushort4v*)(gp);
    gxc[1] = *(const ushort4v*)(gp + 128);
    gxc[2] = *(const ushort4v*)(gp + 256);
  }
  int tok1 = xs[BATCH + ng];

  // h' write offset (B-fragment order): frag kf=j>>5, sublane q_b=(j>>3)&3, i=j&7
  const int kfw = j0 >> 5, qb = (j0 >> 3) & 3, i0 = j0 & 7;
  const int wofs = (kfw * 64 + qb * 16 + ln) * 8 + i0;

  const float NL2E = -1.442695041f;

  __syncthreads();

#pragma unroll 2
  for (int s = 0; s < S_LEN; ++s) {
    // next-step gx gather (unconditional; stays in flight across barrier)
    {
      const unsigned short* gp = gxv + (size_t)tok1 * G3 + j0;
      gxn[0] = *(const ushort4v*)(gp);
      gxn[1] = *(const ushort4v*)(gp + 128);
      gxn[2] = *(const ushort4v*)(gp + 256);
    }
    const int s2 = (s + 2 < S_LEN) ? (s + 2) : 0;   // uniform clamp, branchless
    const int tok2 = xs[s2 * BATCH + ng];

    // B fragments: h^T, B[k = quad*8+i][n = lane&15], pre-swizzled in LDS
    const unsigned short* rb = hbuf[s & 1];
    short8 bfrag[4];
#pragma unroll
    for (int kf = 0; kf < 4; ++kf)
      bfrag[kf] = *(const short8*)(rb + (kf * 64 + L) * 8);

    // 2 independent 2-deep MFMA chains per gate (halves dep-chain latency)
    float4v acc[3];
#pragma unroll
    for (int t = 0; t < 3; ++t) {
      float4v a0 = {0.f, 0.f, 0.f, 0.f};
      float4v a1 = {0.f, 0.f, 0.f, 0.f};
      a0 = __builtin_amdgcn_mfma_f32_16x16x32_bf16(afrag[t][0], bfrag[0], a0, 0, 0, 0);
      a1 = __builtin_amdgcn_mfma_f32_16x16x32_bf16(afrag[t][1], bfrag[1], a1, 0, 0, 0);
      a0 = __builtin_amdgcn_mfma_f32_16x16x32_bf16(afrag[t][2], bfrag[2], a0, 0, 0, 0);
      a1 = __builtin_amdgcn_mfma_f32_16x16x32_bf16(afrag[t][3], bfrag[3], a1, 0, 0, 0);
      acc[t] = a0 + a1;
    }

    // gates, packed f32 (pairs of rows): lane holds rows j0..j0+3, col ng
#pragma unroll
    for (int p = 0; p < 2; ++p) {
      const int r0 = 2 * p, r1 = 2 * p + 1;
      const float2v gx0 = {bf2f(gxc[0][r0]), bf2f(gxc[0][r1])};
      const float2v gx1 = {bf2f(gxc[1][r0]), bf2f(gxc[1][r1])};
      const float2v gx2 = {bf2f(gxc[2][r0]), bf2f(gxc[2][r1])};
      const float2v A0 = {acc[0][r0], acc[0][r1]};
      const float2v A1 = {acc[1][r0], acc[1][r1]};
      const float2v A2 = {acc[2][r0], acc[2][r1]};
      const float2v gr  = gx0 + A0;               // b_hr folded in gxv
      const float2v gz  = gx1 + A1;               // b_hz folded in gxv
      const float2v ghn = A2 + bhn2[p];
      const float2v tr = gr * NL2E;
      const float2v er = {__builtin_amdgcn_exp2f(tr.x), __builtin_amdgcn_exp2f(tr.y)};
      const float2v dr = er + 1.f;
      const float2v rg = {__builtin_amdgcn_rcpf(dr.x), __builtin_amdgcn_rcpf(dr.y)};
      const float2v tz = gz * NL2E;
      const float2v ez = {__builtin_amdgcn_exp2f(tz.x), __builtin_amdgcn_exp2f(tz.y)};
      const float2v dz = ez + 1.f;
      const float2v zg = {__builtin_amdgcn_rcpf(dz.x), __builtin_amdgcn_rcpf(dz.y)};
      const float2v pre = gx2 + rg * ghn;
      const float2v tn = pre * (2.f * NL2E);
      const float2v en = {__builtin_amdgcn_exp2f(tn.x), __builtin_amdgcn_exp2f(tn.y)};
      const float2v dn = en + 1.f;
      const float2v sg = {__builtin_amdgcn_rcpf(dn.x), __builtin_amdgcn_rcpf(dn.y)};
      const float2v nn = sg * 2.f - 1.f;          // tanh via sigmoid
      h2[p] = zg * (h2[p] - nn) + nn;             // pk_sub + pk_fma
    }

    // pack 4 fp32 -> 4 bf16 (round-half-up) via 2x v_perm_b32
    const uint32_t p0 = __builtin_amdgcn_perm(fbits(h2[0].y) + 0x8000u,
                                              fbits(h2[0].x) + 0x8000u, 0x07060302u);
    const uint32_t p1 = __builtin_amdgcn_perm(fbits(h2[1].y) + 0x8000u,
                                              fbits(h2[1].x) + 0x8000u, 0x07060302u);
    uint2v hv; hv[0] = p0; hv[1] = p1;
    *(uint2v*)(hbuf[(s + 1) & 1] + wofs) = hv;

    // LDS-only barrier: do NOT drain vmcnt — gx prefetch stays in flight
    asm volatile("s_waitcnt lgkmcnt(0)\n\ts_barrier" ::: "memory");

#pragma unroll
    for (int t = 0; t < 3; ++t) gxc[t] = gxn[t];
    tok1 = tok2;
  }

  // final h -> fcin[b][gru*128 + j]
  float4v hv = {h2[0].x, h2[0].y, h2[1].x, h2[1].y};
  *(float4v*)(fcin + (size_t)ng * 256 + gru * 128 + j0) = hv;
}

// ---------------------------------------------------------------------------
// Kernel C: out[b] = sigmoid(b2 + W2 . relu(b1 + W1 . fcin[b]))
// ---------------------------------------------------------------------------
__global__ __launch_bounds__(128) void head_kernel(
    const float* __restrict__ fcin, const float* __restrict__ W1,
    const float* __restrict__ b1, const float* __restrict__ W2,
    const float* __restrict__ b2, float* __restrict__ out) {
  __shared__ float fc[256];
  __shared__ float part[2];
  const int b = blockIdx.x, t = threadIdx.x;
  fc[t]       = fcin[(size_t)b * 256 + t];
  fc[t + 128] = fcin[(size_t)b * 256 + t + 128];
  __syncthreads();

  float acc = b1[t];
#pragma unroll 8
  for (int k = 0; k < 256; ++k) acc += W1[t * 256 + k] * fc[k];
  const float hid = fmaxf(acc, 0.f);

  float v = hid * W2[t];
#pragma unroll
  for (int o = 32; o > 0; o >>= 1) v += __shfl_xor(v, o, 64);
  if ((t & 63) == 0) part[t >> 6] = v;
  __syncthreads();
  if (t == 0) {
    const float s = part[0] + part[1] + b2[0];
    out[b] = fast_sig(s);
  }
}

// ---------------------------------------------------------------------------
extern "C" void kernel_launch(void* const* d_in, const int* in_sizes, int n_in,
                              void* d_out, int out_size, void* d_ws, size_t ws_size,
                              hipStream_t stream) {
  const int*   x1   = (const int*)d_in[0];
  const int*   x2   = (const int*)d_in[1];
  const float* emb  = (const float*)d_in[2];
  const float* W_ih = (const float*)d_in[3];
  const float* W_hh = (const float*)d_in[4];
  const float* b_ih = (const float*)d_in[5];
  const float* b_hh = (const float*)d_in[6];
  const float* W1   = (const float*)d_in[7];
  const float* b1   = (const float*)d_in[8];
  const float* W2   = (const float*)d_in[9];
  const float* b2   = (const float*)d_in[10];
  float* out = (float*)d_out;

  unsigned short* gxv = (unsigned short*)d_ws;                  // 50000*384*2 = 38.4 MB
  float* fcin = (float*)((char*)d_ws + (size_t)VOC * G3 * 2);   // 512*256*4 = 512 KB

  build_gxv<<<(VOC + 127) / 128, 192, 0, stream>>>(emb, W_ih, b_ih, b_hh, gxv);
  gru_kernel<<<64, 512, 0, stream>>>(x1, x2, gxv, W_hh, b_hh, fcin);
  head_kernel<<<512, 128, 0, stream>>>(fcin, W1, b1, W2, b2, out);
}

// Round 4
// 497.066 us; speedup vs baseline: 1.4675x; 1.2039x over previous
//
#include <hip/hip_runtime.h>
#include <hip/hip_bf16.h>
#include <stdint.h>

#define S_LEN 512
#define BATCH 512
#define HID   128
#define G3    384
#define EMB   50
#define VOC   50000

typedef __attribute__((ext_vector_type(8))) short short8;
typedef __attribute__((ext_vector_type(4))) float float4v;
typedef __attribute__((ext_vector_type(2))) float float2v;
typedef __attribute__((ext_vector_type(4))) unsigned short ushort4v;
typedef __attribute__((ext_vector_type(2))) uint32_t uint2v;

__device__ inline unsigned short f2bf(float f) {
  union { float f; uint32_t u; } v; v.f = f;
  uint32_t u = v.u;
  u += 0x7fffu + ((u >> 16) & 1u);   // RNE
  return (unsigned short)(u >> 16);
}
__device__ inline uint32_t fbits(float f) {
  union { float f; uint32_t u; } v; v.f = f; return v.u;
}
__device__ inline float fast_sig(float x) {
  return __builtin_amdgcn_rcpf(1.f + __expf(-x));
}
// bf16 pair (packed in one dword: lo=elem0, hi=elem1) -> float2
__device__ inline float2v bfpair(uint32_t dw) {
  union { uint32_t u; float f; } lo, hi;
  lo.u = dw << 16; hi.u = dw & 0xffff0000u;
  return (float2v){lo.f, hi.f};
}
// ---- true packed-f32 math (VOP3P); LLVM scalarizes generic vector ops ----
__device__ inline float2v pk_add(float2v a, float2v b) {
  float2v d; asm("v_pk_add_f32 %0, %1, %2" : "=v"(d) : "v"(a), "v"(b)); return d;
}
__device__ inline float2v pk_sub(float2v a, float2v b) {
  float2v d;
  asm("v_pk_add_f32 %0, %1, %2 neg_lo:[0,1] neg_hi:[0,1]" : "=v"(d) : "v"(a), "v"(b));
  return d;
}
__device__ inline float2v pk_mul(float2v a, float2v b) {
  float2v d; asm("v_pk_mul_f32 %0, %1, %2" : "=v"(d) : "v"(a), "v"(b)); return d;
}
__device__ inline float2v pk_fma(float2v a, float2v b, float2v c) {
  float2v d; asm("v_pk_fma_f32 %0, %1, %2, %3" : "=v"(d) : "v"(a), "v"(b), "v"(c)); return d;
}

// load 8 consecutive floats from row[k0..k0+7], zero-padded past EMB, as bf16
__device__ inline short8 load8_bf_padded(const float* __restrict__ row, int k0) {
  float f[8];
  if (k0 + 7 < EMB) {
    float4v a = *(const float4v*)(row + k0);
    float4v b = *(const float4v*)(row + k0 + 4);
#pragma unroll
    for (int i = 0; i < 4; ++i) { f[i] = a[i]; f[i + 4] = b[i]; }
  } else {
#pragma unroll
    for (int i = 0; i < 8; ++i) f[i] = (k0 + i < EMB) ? row[k0 + i] : 0.f;
  }
  short8 s;
#pragma unroll
  for (int i = 0; i < 8; ++i) s[i] = (short)f2bf(f[i]);
  return s;
}

// ---------------------------------------------------------------------------
// Kernel A (MFMA): gxv[v][g] = b_ih[g] + (g<256 ? b_hh[g] : 0)
//                              + sum_e W_ih[g][e] * emb[v][e]
// GEMM: A = emb (M=vocab), B = W_ih^T (N=384 gates), K = 64 (EMB=50 zero-pad).
// Bias folded into MFMA C-init (free). Block = 4 waves x 16 vocab rows.
// ---------------------------------------------------------------------------
__global__ __launch_bounds__(256) void build_gxv(
    const float* __restrict__ emb, const float* __restrict__ W_ih,
    const float* __restrict__ b_ih, const float* __restrict__ b_hh,
    unsigned short* __restrict__ gxv) {
  const int w  = threadIdx.x >> 6;
  const int L  = threadIdx.x & 63;
  const int q  = L >> 4;
  const int ln = L & 15;
  const int vbase = blockIdx.x * 64 + w * 16;

  // A fragments: A[m=ln][k=q*8+i] = emb[vbase+ln][k], k zero-padded to 64
  const int vr = min(vbase + ln, VOC - 1);
  const float* arow = emb + (size_t)vr * EMB;
  short8 afr[2];
  afr[0] = load8_bf_padded(arow, q * 8);
  afr[1] = load8_bf_padded(arow, 32 + q * 8);

  const int g = ln;  // column-in-tile -> gate = nt*16 + ln
  for (int nt = 0; nt < 24; ++nt) {
    const int gg = nt * 16 + g;
    const float* brow = W_ih + (size_t)gg * EMB;
    short8 bfr0 = load8_bf_padded(brow, q * 8);
    short8 bfr1 = load8_bf_padded(brow, 32 + q * 8);
    const float bias = b_ih[gg] + (gg < 256 ? b_hh[gg] : 0.f);
    float4v acc = {bias, bias, bias, bias};
    acc = __builtin_amdgcn_mfma_f32_16x16x32_bf16(afr[0], bfr0, acc, 0, 0, 0);
    acc = __builtin_amdgcn_mfma_f32_16x16x32_bf16(afr[1], bfr1, acc, 0, 0, 0);
    // C: col = ln (gate), row = q*4 + r (vocab-in-tile)
#pragma unroll
    for (int r = 0; r < 4; ++r) {
      const int row = vbase + q * 4 + r;
      if (row < VOC) gxv[(size_t)row * G3 + gg] = f2bf(acc[r]);
    }
  }
}

// ---------------------------------------------------------------------------
// Kernel B: persistent GRU recurrence. 64 blocks = 2 GRUs x 32 batch-chunks.
// Block: 512 threads (8 waves). Wave w owns hidden units j in [16w,16w+16):
//   A-fragments (resident): W_hh rows {j, 128+j, 256+j} x K=128, bf16.
// Per step: gh^T = W_hh * h^T via 12 mfma_f32_16x16x32_bf16 per wave
// (2 independent 2-deep chains per gate); gate math in C-layout with REAL
// v_pk_*_f32 (inline asm; compiler scalarizes generic vector f32 ops);
// h fp32 in regs; bf16 h^T via double-buffered LDS in B-frag order;
// lgkm-only barrier keeps gx prefetch in flight.
// ---------------------------------------------------------------------------
__global__ __launch_bounds__(512) void gru_kernel(
    const int* __restrict__ x1, const int* __restrict__ x2,
    const unsigned short* __restrict__ gxv, const float* __restrict__ W_hh,
    const float* __restrict__ b_hh, float* __restrict__ fcin) {
  const int bid   = blockIdx.x;
  const int gru   = bid >> 5;
  const int chunk = bid & 31;
  const int* xs   = gru ? x2 : x1;

  const int tid = threadIdx.x;
  const int w  = tid >> 6;        // wave 0..7
  const int L  = tid & 63;        // lane
  const int q  = L >> 4;          // quad 0..3
  const int ln = L & 15;          // n (batch within chunk)
  const int jb = w * 16;
  const int j0 = jb + q * 4;      // this lane's 4 hidden units j0..j0+3
  const int ng = chunk * 16 + ln; // global batch index

  __shared__ __align__(16) unsigned short hbuf[2][2048]; // 2 x 4KB h^T B-frag buffers

  // --- resident A fragments: A[m = lane&15][k = quad*8 + i] per 16x16x32 ---
  short8 afrag[3][4];
#pragma unroll
  for (int t = 0; t < 3; ++t) {
    const float* wr = W_hh + (size_t)(t * 128 + jb + ln) * HID;
#pragma unroll
    for (int kf = 0; kf < 4; ++kf) {
      const int k0 = kf * 32 + q * 8;
      float4v f0 = *(const float4v*)(wr + k0);
      float4v f1 = *(const float4v*)(wr + k0 + 4);
      short8 a;
#pragma unroll
      for (int i = 0; i < 4; ++i) a[i] = (short)f2bf(f0[i]);
#pragma unroll
      for (int i = 0; i < 4; ++i) a[i + 4] = (short)f2bf(f1[i]);
      afrag[t][kf] = a;
    }
  }

  float2v bhn2[2];
#pragma unroll
  for (int p = 0; p < 2; ++p) {
    bhn2[p].x = b_hh[2 * 128 + j0 + 2 * p];
    bhn2[p].y = b_hh[2 * 128 + j0 + 2 * p + 1];
  }

  // zero both h buffers (h0 = 0)
  for (int idx = tid; idx < 4096; idx += 512) ((unsigned short*)hbuf)[idx] = 0;

  float2v h2[2];
  h2[0] = (float2v){0.f, 0.f};
  h2[1] = (float2v){0.f, 0.f};

  // gx prefetch: tokens two ahead, gx one ahead.  gx held as 2 dwords/gate
  // (each dword = bf16 pair for rows 2p,2p+1)
  const int tok0 = xs[ng];
  uint2v gxc[3], gxn[3];
  {
    const unsigned short* gp = gxv + (size_t)tok0 * G3 + j0;
    gxc[0] = *(const uint2v*)(gp);
    gxc[1] = *(const uint2v*)(gp + 128);
    gxc[2] = *(const uint2v*)(gp + 256);
  }
  int tok1 = xs[BATCH + ng];

  // h' write offset (B-fragment order): frag kf=j>>5, sublane q_b=(j>>3)&3, i=j&7
  const int kfw = j0 >> 5, qb = (j0 >> 3) & 3, i0 = j0 & 7;
  const int wofs = (kfw * 64 + qb * 16 + ln) * 8 + i0;

  const float2v NL2E2  = {-1.442695041f, -1.442695041f};
  const float2v N2L2E2 = {-2.885390082f, -2.885390082f};
  const float2v K_ONE  = {1.f, 1.f};
  const float2v K_TWO  = {2.f, 2.f};
  const float2v K_MONE = {-1.f, -1.f};

  __syncthreads();

#pragma unroll 2
  for (int s = 0; s < S_LEN; ++s) {
    // next-step gx gather (stays in flight across the lgkm-only barrier)
    {
      const unsigned short* gp = gxv + (size_t)tok1 * G3 + j0;
      gxn[0] = *(const uint2v*)(gp);
      gxn[1] = *(const uint2v*)(gp + 128);
      gxn[2] = *(const uint2v*)(gp + 256);
    }
    const int s2 = (s + 2 < S_LEN) ? (s + 2) : 0;   // uniform clamp, branchless
    const int tok2 = xs[s2 * BATCH + ng];

    // B fragments: h^T, B[k = quad*8+i][n = lane&15], pre-swizzled in LDS
    const unsigned short* rb = hbuf[s & 1];
    short8 bfrag[4];
#pragma unroll
    for (int kf = 0; kf < 4; ++kf)
      bfrag[kf] = *(const short8*)(rb + (kf * 64 + L) * 8);

    // 2 independent 2-deep MFMA chains per gate
    float4v acc[3];
#pragma unroll
    for (int t = 0; t < 3; ++t) {
      float4v a0 = {0.f, 0.f, 0.f, 0.f};
      float4v a1 = {0.f, 0.f, 0.f, 0.f};
      a0 = __builtin_amdgcn_mfma_f32_16x16x32_bf16(afrag[t][0], bfrag[0], a0, 0, 0, 0);
      a1 = __builtin_amdgcn_mfma_f32_16x16x32_bf16(afrag[t][1], bfrag[1], a1, 0, 0, 0);
      a0 = __builtin_amdgcn_mfma_f32_16x16x32_bf16(afrag[t][2], bfrag[2], a0, 0, 0, 0);
      a1 = __builtin_amdgcn_mfma_f32_16x16x32_bf16(afrag[t][3], bfrag[3], a1, 0, 0, 0);
      // packed combine (2x v_pk_add_f32)
      float2v lo = pk_add((float2v){a0[0], a0[1]}, (float2v){a1[0], a1[1]});
      float2v hi = pk_add((float2v){a0[2], a0[3]}, (float2v){a1[2], a1[3]});
      acc[t] = (float4v){lo.x, lo.y, hi.x, hi.y};
    }

    // gates, genuinely packed: lane holds rows j0..j0+3, col ng
#pragma unroll
    for (int p = 0; p < 2; ++p) {
      const float2v gx0 = bfpair(gxc[0][p]);
      const float2v gx1 = bfpair(gxc[1][p]);
      const float2v gx2 = bfpair(gxc[2][p]);
      const float2v A0 = {acc[0][2 * p], acc[0][2 * p + 1]};
      const float2v A1 = {acc[1][2 * p], acc[1][2 * p + 1]};
      const float2v A2 = {acc[2][2 * p], acc[2][2 * p + 1]};
      const float2v gr  = pk_add(gx0, A0);        // b_hr folded in gxv
      const float2v gz  = pk_add(gx1, A1);        // b_hz folded in gxv
      const float2v ghn = pk_add(A2, bhn2[p]);
      const float2v tr = pk_mul(gr, NL2E2);
      const float2v er = {__builtin_amdgcn_exp2f(tr.x), __builtin_amdgcn_exp2f(tr.y)};
      const float2v dr = pk_add(er, K_ONE);
      const float2v rg = {__builtin_amdgcn_rcpf(dr.x), __builtin_amdgcn_rcpf(dr.y)};
      const float2v tz = pk_mul(gz, NL2E2);
      const float2v ez = {__builtin_amdgcn_exp2f(tz.x), __builtin_amdgcn_exp2f(tz.y)};
      const float2v dz = pk_add(ez, K_ONE);
      const float2v zg = {__builtin_amdgcn_rcpf(dz.x), __builtin_amdgcn_rcpf(dz.y)};
      const float2v pre = pk_fma(rg, ghn, gx2);
      const float2v tn = pk_mul(pre, N2L2E2);
      const float2v en = {__builtin_amdgcn_exp2f(tn.x), __builtin_amdgcn_exp2f(tn.y)};
      const float2v dn = pk_add(en, K_ONE);
      const float2v sg = {__builtin_amdgcn_rcpf(dn.x), __builtin_amdgcn_rcpf(dn.y)};
      const float2v nn = pk_fma(sg, K_TWO, K_MONE);   // tanh via sigmoid
      const float2v df = pk_sub(h2[p], nn);
      h2[p] = pk_fma(zg, df, nn);
    }

    // pack 4 fp32 -> 4 bf16 (round-half-up) via 2x v_perm_b32
    const uint32_t p0 = __builtin_amdgcn_perm(fbits(h2[0].y) + 0x8000u,
                                              fbits(h2[0].x) + 0x8000u, 0x07060302u);
    const uint32_t p1 = __builtin_amdgcn_perm(fbits(h2[1].y) + 0x8000u,
                                              fbits(h2[1].x) + 0x8000u, 0x07060302u);
    uint2v hv; hv[0] = p0; hv[1] = p1;
    *(uint2v*)(hbuf[(s + 1) & 1] + wofs) = hv;

    // LDS-only barrier: do NOT drain vmcnt — gx prefetch stays in flight
    asm volatile("s_waitcnt lgkmcnt(0)\n\ts_barrier" ::: "memory");

#pragma unroll
    for (int t = 0; t < 3; ++t) gxc[t] = gxn[t];
    tok1 = tok2;
  }

  // final h -> fcin[b][gru*128 + j]
  float4v hv = {h2[0].x, h2[0].y, h2[1].x, h2[1].y};
  *(float4v*)(fcin + (size_t)ng * 256 + gru * 128 + j0) = hv;
}

// ---------------------------------------------------------------------------
// Kernel C: out[b] = sigmoid(b2 + W2 . relu(b1 + W1 . fcin[b]))
// ---------------------------------------------------------------------------
__global__ __launch_bounds__(128) void head_kernel(
    const float* __restrict__ fcin, const float* __restrict__ W1,
    const float* __restrict__ b1, const float* __restrict__ W2,
    const float* __restrict__ b2, float* __restrict__ out) {
  __shared__ float fc[256];
  __shared__ float part[2];
  const int b = blockIdx.x, t = threadIdx.x;
  fc[t]       = fcin[(size_t)b * 256 + t];
  fc[t + 128] = fcin[(size_t)b * 256 + t + 128];
  __syncthreads();

  float acc = b1[t];
#pragma unroll 8
  for (int k = 0; k < 256; ++k) acc += W1[t * 256 + k] * fc[k];
  const float hid = fmaxf(acc, 0.f);

  float v = hid * W2[t];
#pragma unroll
  for (int o = 32; o > 0; o >>= 1) v += __shfl_xor(v, o, 64);
  if ((t & 63) == 0) part[t >> 6] = v;
  __syncthreads();
  if (t == 0) {
    const float s = part[0] + part[1] + b2[0];
    out[b] = fast_sig(s);
  }
}

// ---------------------------------------------------------------------------
extern "C" void kernel_launch(void* const* d_in, const int* in_sizes, int n_in,
                              void* d_out, int out_size, void* d_ws, size_t ws_size,
                              hipStream_t stream) {
  const int*   x1   = (const int*)d_in[0];
  const int*   x2   = (const int*)d_in[1];
  const float* emb  = (const float*)d_in[2];
  const float* W_ih = (const float*)d_in[3];
  const float* W_hh = (const float*)d_in[4];
  const float* b_ih = (const float*)d_in[5];
  const float* b_hh = (const float*)d_in[6];
  const float* W1   = (const float*)d_in[7];
  const float* b1   = (const float*)d_in[8];
  const float* W2   = (const float*)d_in[9];
  const float* b2   = (const float*)d_in[10];
  float* out = (float*)d_out;

  unsigned short* gxv = (unsigned short*)d_ws;                  // 50000*384*2 = 38.4 MB
  float* fcin = (float*)((char*)d_ws + (size_t)VOC * G3 * 2);   // 512*256*4 = 512 KB

  build_gxv<<<(VOC + 63) / 64, 256, 0, stream>>>(emb, W_ih, b_ih, b_hh, gxv);
  gru_kernel<<<64, 512, 0, stream>>>(x1, x2, gxv, W_hh, b_hh, fcin);
  head_kernel<<<512, 128, 0, stream>>>(fcin, W1, b1, W2, b2, out);
}

// Round 5
// 414.312 us; speedup vs baseline: 1.7607x; 1.1997x over previous
//
#include <hip/hip_runtime.h>
#include <hip/hip_bf16.h>
#include <stdint.h>

#define S_LEN 512
#define BATCH 512
#define HID   128
#define G3    384
#define EMB   50
#define VOC   50000

typedef __attribute__((ext_vector_type(8))) short short8;
typedef __attribute__((ext_vector_type(4))) float float4v;

__device__ inline unsigned short f2bf(float f) {
  union { float f; uint32_t u; } v; v.f = f;
  uint32_t u = v.u;
  u += 0x7fffu + ((u >> 16) & 1u);   // RNE
  return (unsigned short)(u >> 16);
}
__device__ inline float bf2f(unsigned short h) {
  union { uint32_t u; float f; } v; v.u = ((uint32_t)h) << 16;
  return v.f;
}
__device__ inline uint32_t fbits(float f) {
  union { float f; uint32_t u; } v; v.f = f; return v.u;
}
__device__ inline float fast_sig(float x) {
  return __builtin_amdgcn_rcpf(1.f + __expf(-x));
}

// load 8 consecutive floats from row[k0..k0+7], zero-padded past EMB, as bf16
__device__ inline short8 load8_bf_padded(const float* __restrict__ row, int k0) {
  float f[8];
  if (k0 + 7 < EMB) {
    float4v a = *(const float4v*)(row + k0);
    float4v b = *(const float4v*)(row + k0 + 4);
#pragma unroll
    for (int i = 0; i < 4; ++i) { f[i] = a[i]; f[i + 4] = b[i]; }
  } else {
#pragma unroll
    for (int i = 0; i < 8; ++i) f[i] = (k0 + i < EMB) ? row[k0 + i] : 0.f;
  }
  short8 s;
#pragma unroll
  for (int i = 0; i < 8; ++i) s[i] = (short)f2bf(f[i]);
  return s;
}

// ---------------------------------------------------------------------------
// Kernel A (MFMA): gxv[v][g] = b_ih[g] + (g<256 ? b_hh[g] : 0)
//                              + sum_e W_ih[g][e] * emb[v][e]
// v3: C tile staged in LDS (bf16), then fully-coalesced 16B/lane bulk store
// (v2's 2B/lane scatter stores were the cost).
// ---------------------------------------------------------------------------
__global__ __launch_bounds__(256) void build_gxv(
    const float* __restrict__ emb, const float* __restrict__ W_ih,
    const float* __restrict__ b_ih, const float* __restrict__ b_hh,
    unsigned short* __restrict__ gxv) {
  __shared__ __align__(16) unsigned short cmat[64][392];  // 64 vocab rows, +8 pad
  const int w  = threadIdx.x >> 6;
  const int L  = threadIdx.x & 63;
  const int q  = L >> 4;
  const int ln = L & 15;
  const int vbase = blockIdx.x * 64 + w * 16;
  const int vloc  = w * 16;

  // A fragments: A[m=ln][k=q*8+i] = emb[vbase+ln][k], k zero-padded to 64
  const int vr = min(vbase + ln, VOC - 1);
  const float* arow = emb + (size_t)vr * EMB;
  short8 afr0 = load8_bf_padded(arow, q * 8);
  short8 afr1 = load8_bf_padded(arow, 32 + q * 8);

  for (int nt = 0; nt < 24; ++nt) {
    const int gg = nt * 16 + ln;
    const float* brow = W_ih + (size_t)gg * EMB;
    short8 b0 = load8_bf_padded(brow, q * 8);
    short8 b1 = load8_bf_padded(brow, 32 + q * 8);
    const float bias = b_ih[gg] + (gg < 256 ? b_hh[gg] : 0.f);
    float4v acc = {bias, bias, bias, bias};
    acc = __builtin_amdgcn_mfma_f32_16x16x32_bf16(afr0, b0, acc, 0, 0, 0);
    acc = __builtin_amdgcn_mfma_f32_16x16x32_bf16(afr1, b1, acc, 0, 0, 0);
    // C: col = ln (gate), row = q*4 + r (vocab-in-tile) -> stage in LDS
#pragma unroll
    for (int r = 0; r < 4; ++r)
      cmat[vloc + q * 4 + r][gg] = f2bf(acc[r]);
  }
  __syncthreads();

  // coalesced bulk store: 64 rows x 384 ushorts = 3072 chunks of 16B
  for (int idx = threadIdx.x; idx < 3072; idx += 256) {
    const int row = idx / 48, c8 = idx - row * 48;
    const int vrow = blockIdx.x * 64 + row;
    if (vrow < VOC) {
      short8 v = *(const short8*)(&cmat[row][c8 * 8]);
      *(short8*)(gxv + (size_t)vrow * G3 + c8 * 8) = v;
    }
  }
}

// ---------------------------------------------------------------------------
// Kernel B: persistent GRU recurrence. 256 blocks = 2 GRUs x 128 chunks of
// FOUR batch columns -> 1 block/CU, full chip. Block: 512 threads (8 waves).
// Wave w owns hidden units j in [16w,16w+16): resident W_hh A-fragments.
// Per step: gh^T via 12 mfma_f32_16x16x32_bf16 (B cols 4..15 are broadcast
// duplicates of cols 0..3 -> same-address LDS reads, free); C fragments
// repacked through wave-private LDS scratch to 1 gate-element per lane
// (cuts transcendental issue 4x vs chunk=16); h fp32, 1/lane; h^T bf16 via
// 2x1KB double-buffered LDS in packed B-frag order; lgkm-only barrier.
// ---------------------------------------------------------------------------
__global__ __launch_bounds__(512) void gru_kernel(
    const int* __restrict__ x1, const int* __restrict__ x2,
    const unsigned short* __restrict__ gxv, const float* __restrict__ W_hh,
    const float* __restrict__ b_hh, float* __restrict__ fcin) {
  const int bid   = blockIdx.x;
  const int gru   = bid >> 7;         // 0..1
  const int chunk = bid & 127;        // 0..127
  const int* xs   = gru ? x2 : x1;

  const int tid = threadIdx.x;
  const int w  = tid >> 6;            // wave 0..7
  const int L  = tid & 63;            // lane
  const int q  = L >> 4;              // C-layout quad
  const int ln = L & 15;              // C-layout col (valid cols ln<4)
  const int jb = w * 16;
  // repack assignment: this lane owns element (j, n)
  const int jl = L >> 2, n = L & 3;
  const int j  = jb + jl;
  const int ng = chunk * 4 + n;       // global batch index

  __shared__ __align__(16) unsigned short hbuf[2][512]; // h^T packed B-frags (4 cols)
  __shared__ float scr[3][128][4];                      // repack scratch [gate][j][n]

  // --- resident A fragments: A[m = ln][k = q*8 + i] per 16x16x32 ---
  short8 afrag[3][4];
#pragma unroll
  for (int t = 0; t < 3; ++t) {
    const float* wr = W_hh + (size_t)(t * 128 + jb + ln) * HID;
#pragma unroll
    for (int kf = 0; kf < 4; ++kf) {
      const int k0 = kf * 32 + q * 8;
      float4v f0 = *(const float4v*)(wr + k0);
      float4v f1 = *(const float4v*)(wr + k0 + 4);
      short8 a;
#pragma unroll
      for (int i = 0; i < 4; ++i) a[i] = (short)f2bf(f0[i]);
#pragma unroll
      for (int i = 0; i < 4; ++i) a[i + 4] = (short)f2bf(f1[i]);
      afrag[t][kf] = a;
    }
  }

  const float bhn = b_hh[2 * 128 + j];

  // zero both h buffers (h0 = 0)
  for (int idx = tid; idx < 1024; idx += 512) ((unsigned short*)hbuf)[idx] = 0;

  float h = 0.f;

  // gx prefetch: tokens two ahead, gx one ahead (3 bf16 scalars per lane)
  const int tok0 = xs[ng];
  unsigned short gxr, gxz, gxnn;
  {
    const unsigned short* gp = gxv + (size_t)tok0 * G3;
    gxr = gp[j]; gxz = gp[128 + j]; gxnn = gp[256 + j];
  }
  int tok1 = xs[BATCH + ng];

  // h' write offset in packed B-frag order: ((j>>3)*4 + n)*8 + (j&7)
  const int wofs = (((j >> 3) * 4 + n) << 3) + (j & 7);
  // B-frag read offset: cols >=4 alias col&3 (LDS same-address broadcast)
  const int rofs = ((q * 4 + (ln & 3)) << 3);

  __syncthreads();

  for (int s = 0; s < S_LEN; ++s) {
    // next-step gx gather (stays in flight across the lgkm-only barrier)
    unsigned short pr, pz, pn;
    {
      const unsigned short* gp = gxv + (size_t)tok1 * G3;
      pr = gp[j]; pz = gp[128 + j]; pn = gp[256 + j];
    }
    const int s2 = (s + 2 < S_LEN) ? (s + 2) : 0;   // uniform clamp, branchless
    const int tok2 = xs[s2 * BATCH + ng];

    // B fragments from packed h^T buffer
    const unsigned short* rb = hbuf[s & 1];
    short8 bfrag[4];
#pragma unroll
    for (int kf = 0; kf < 4; ++kf)
      bfrag[kf] = *(const short8*)(rb + kf * 128 + rofs);

    // 2 independent 2-deep MFMA chains per gate
    float4v acc[3];
#pragma unroll
    for (int t = 0; t < 3; ++t) {
      float4v a0 = {0.f, 0.f, 0.f, 0.f};
      float4v a1 = {0.f, 0.f, 0.f, 0.f};
      a0 = __builtin_amdgcn_mfma_f32_16x16x32_bf16(afrag[t][0], bfrag[0], a0, 0, 0, 0);
      a1 = __builtin_amdgcn_mfma_f32_16x16x32_bf16(afrag[t][1], bfrag[1], a1, 0, 0, 0);
      a0 = __builtin_amdgcn_mfma_f32_16x16x32_bf16(afrag[t][2], bfrag[2], a0, 0, 0, 0);
      a1 = __builtin_amdgcn_mfma_f32_16x16x32_bf16(afrag[t][3], bfrag[3], a1, 0, 0, 0);
      acc[t] = a0 + a1;
    }

    // repack: valid C cols live in lanes ln<4; scatter to wave-private scratch
    if (ln < 4) {
#pragma unroll
      for (int t = 0; t < 3; ++t)
#pragma unroll
        for (int r = 0; r < 4; ++r)
          scr[t][jb + q * 4 + r][ln] = acc[t][r];
    }
    // wave-private RAW: compiler inserts lgkmcnt wait; no barrier needed
    const float aR = scr[0][j][n];
    const float aZ = scr[1][j][n];
    const float aN = scr[2][j][n];

    // gate math: exactly 1 hidden element per lane
    const float gr  = bf2f(gxr) + aR;        // b_hr folded in gxv
    const float gz  = bf2f(gxz) + aZ;        // b_hz folded in gxv
    const float ghn = aN + bhn;
    const float rg  = fast_sig(gr);
    const float zg  = fast_sig(gz);
    const float pre = bf2f(gxnn) + rg * ghn;
    const float nn  = 2.f * fast_sig(2.f * pre) - 1.f;   // tanh via sigmoid
    h = zg * (h - nn) + nn;

    // write h' as bf16 (round-half-up)
    hbuf[(s + 1) & 1][wofs] = (unsigned short)((fbits(h) + 0x8000u) >> 16);

    // LDS-only barrier: do NOT drain vmcnt — gx prefetch stays in flight
    asm volatile("s_waitcnt lgkmcnt(0)\n\ts_barrier" ::: "memory");

    gxr = pr; gxz = pz; gxnn = pn;
    tok1 = tok2;
  }

  // final h -> fcin[b][gru*128 + j]
  fcin[(size_t)ng * 256 + gru * 128 + j] = h;
}

// ---------------------------------------------------------------------------
// Kernel C: out[b] = sigmoid(b2 + W2 . relu(b1 + W1 . fcin[b]))
// ---------------------------------------------------------------------------
__global__ __launch_bounds__(128) void head_kernel(
    const float* __restrict__ fcin, const float* __restrict__ W1,
    const float* __restrict__ b1, const float* __restrict__ W2,
    const float* __restrict__ b2, float* __restrict__ out) {
  __shared__ float fc[256];
  __shared__ float part[2];
  const int b = blockIdx.x, t = threadIdx.x;
  fc[t]       = fcin[(size_t)b * 256 + t];
  fc[t + 128] = fcin[(size_t)b * 256 + t + 128];
  __syncthreads();

  float acc = b1[t];
#pragma unroll 8
  for (int k = 0; k < 256; ++k) acc += W1[t * 256 + k] * fc[k];
  const float hid = fmaxf(acc, 0.f);

  float v = hid * W2[t];
#pragma unroll
  for (int o = 32; o > 0; o >>= 1) v += __shfl_xor(v, o, 64);
  if ((t & 63) == 0) part[t >> 6] = v;
  __syncthreads();
  if (t == 0) {
    const float s = part[0] + part[1] + b2[0];
    out[b] = fast_sig(s);
  }
}

// ---------------------------------------------------------------------------
extern "C" void kernel_launch(void* const* d_in, const int* in_sizes, int n_in,
                              void* d_out, int out_size, void* d_ws, size_t ws_size,
                              hipStream_t stream) {
  const int*   x1   = (const int*)d_in[0];
  const int*   x2   = (const int*)d_in[1];
  const float* emb  = (const float*)d_in[2];
  const float* W_ih = (const float*)d_in[3];
  const float* W_hh = (const float*)d_in[4];
  const float* b_ih = (const float*)d_in[5];
  const float* b_hh = (const float*)d_in[6];
  const float* W1   = (const float*)d_in[7];
  const float* b1   = (const float*)d_in[8];
  const float* W2   = (const float*)d_in[9];
  const float* b2   = (const float*)d_in[10];
  float* out = (float*)d_out;

  unsigned short* gxv = (unsigned short*)d_ws;                  // 50000*384*2 = 38.4 MB
  float* fcin = (float*)((char*)d_ws + (size_t)VOC * G3 * 2);   // 512*256*4 = 512 KB

  build_gxv<<<(VOC + 63) / 64, 256, 0, stream>>>(emb, W_ih, b_ih, b_hh, gxv);
  gru_kernel<<<256, 512, 0, stream>>>(x1, x2, gxv, W_hh, b_hh, fcin);
  head_kernel<<<512, 128, 0, stream>>>(fcin, W1, b1, W2, b2, out);
}

// Round 6
// 406.965 us; speedup vs baseline: 1.7924x; 1.0181x over previous
//
#include <hip/hip_runtime.h>
#include <hip/hip_bf16.h>
#include <stdint.h>

#define S_LEN 512
#define BATCH 512
#define HID   128
#define G3    384
#define EMB   50
#define VOC   50000

// sigmoid(x) = rcp(1 + exp2(x * -log2(e))); tanh(y) = 2*sigmoid(2y)-1.
// W_hh/gxv rows are PRE-SCALED: r,z rows by NL2E, n rows by N2L2E, so the
// gate math needs no multiplies before exp2.
#define NL2E  (-1.4426950408889634f)
#define N2L2E (-2.8853900817779268f)

typedef __attribute__((ext_vector_type(8))) short short8;
typedef __attribute__((ext_vector_type(4))) float float4v;

__device__ inline unsigned short f2bf(float f) {
  union { float f; uint32_t u; } v; v.f = f;
  uint32_t u = v.u;
  u += 0x7fffu + ((u >> 16) & 1u);   // RNE
  return (unsigned short)(u >> 16);
}
__device__ inline float bf2f(unsigned short h) {
  union { uint32_t u; float f; } v; v.u = ((uint32_t)h) << 16;
  return v.f;
}
__device__ inline uint32_t fbits(float f) {
  union { float f; uint32_t u; } v; v.f = f; return v.u;
}
__device__ inline float fast_sig(float x) {
  return __builtin_amdgcn_rcpf(1.f + __expf(-x));
}

// load 8 floats from row[k0..k0+7], scale, zero-pad past EMB, as bf16
__device__ inline short8 load8_bf_padded(const float* __restrict__ row, int k0,
                                         float sc) {
  float f[8];
  if (k0 + 7 < EMB) {
    float4v a = *(const float4v*)(row + k0);
    float4v b = *(const float4v*)(row + k0 + 4);
#pragma unroll
    for (int i = 0; i < 4; ++i) { f[i] = a[i]; f[i + 4] = b[i]; }
  } else {
#pragma unroll
    for (int i = 0; i < 8; ++i) f[i] = (k0 + i < EMB) ? row[k0 + i] : 0.f;
  }
  short8 s;
#pragma unroll
  for (int i = 0; i < 8; ++i) s[i] = (short)f2bf(f[i] * sc);
  return s;
}

// ---------------------------------------------------------------------------
// Kernel A (MFMA): gxv[v][g] = sc(g) * (b_ih[g] + (g<256 ? b_hh[g] : 0)
//                              + sum_e W_ih[g][e] * emb[v][e])
// sc = NL2E for r,z rows; N2L2E for n rows (pre-scaled sigmoid/tanh args).
// Depth-1 software pipeline on the W_ih row loads; C staged in LDS then
// bulk-stored coalesced.
// ---------------------------------------------------------------------------
__global__ __launch_bounds__(256) void build_gxv(
    const float* __restrict__ emb, const float* __restrict__ W_ih,
    const float* __restrict__ b_ih, const float* __restrict__ b_hh,
    unsigned short* __restrict__ gxv) {
  __shared__ __align__(16) unsigned short cmat[64][392];  // 64 vocab rows, +8 pad
  const int w  = threadIdx.x >> 6;
  const int L  = threadIdx.x & 63;
  const int q  = L >> 4;
  const int ln = L & 15;
  const int vbase = blockIdx.x * 64 + w * 16;
  const int vloc  = w * 16;

  // A fragments: A[m=ln][k=q*8+i] = emb[vbase+ln][k], k zero-padded to 64
  const int vr = min(vbase + ln, VOC - 1);
  const float* arow = emb + (size_t)vr * EMB;
  short8 afr0 = load8_bf_padded(arow, q * 8, 1.f);
  short8 afr1 = load8_bf_padded(arow, 32 + q * 8, 1.f);

  // pipeline: preload nt=0
  int gg = ln;
  float sc = NL2E;
  short8 b0 = load8_bf_padded(W_ih + (size_t)gg * EMB, q * 8, sc);
  short8 b1 = load8_bf_padded(W_ih + (size_t)gg * EMB, 32 + q * 8, sc);
  float bias = sc * (b_ih[gg] + b_hh[gg]);

  for (int nt = 0; nt < 24; ++nt) {
    short8 nb0, nb1; float nbias;
    if (nt < 23) {
      const int g2 = (nt + 1) * 16 + ln;
      const float s2 = (g2 < 256) ? NL2E : N2L2E;
      const float* brow = W_ih + (size_t)g2 * EMB;
      nb0 = load8_bf_padded(brow, q * 8, s2);
      nb1 = load8_bf_padded(brow, 32 + q * 8, s2);
      nbias = s2 * (b_ih[g2] + (g2 < 256 ? b_hh[g2] : 0.f));
    }
    float4v acc = {bias, bias, bias, bias};
    acc = __builtin_amdgcn_mfma_f32_16x16x32_bf16(afr0, b0, acc, 0, 0, 0);
    acc = __builtin_amdgcn_mfma_f32_16x16x32_bf16(afr1, b1, acc, 0, 0, 0);
    // C: col = ln (gate), row = q*4 + r (vocab-in-tile) -> stage in LDS
#pragma unroll
    for (int r = 0; r < 4; ++r)
      cmat[vloc + q * 4 + r][gg] = f2bf(acc[r]);
    gg += 16; b0 = nb0; b1 = nb1; bias = nbias;
  }
  __syncthreads();

  // coalesced bulk store: 64 rows x 384 ushorts = 3072 chunks of 16B
  for (int idx = threadIdx.x; idx < 3072; idx += 256) {
    const int row = idx / 48, c8 = idx - row * 48;
    const int vrow = blockIdx.x * 64 + row;
    if (vrow < VOC) {
      short8 v = *(const short8*)(&cmat[row][c8 * 8]);
      *(short8*)(gxv + (size_t)vrow * G3 + c8 * 8) = v;
    }
  }
}

// ---------------------------------------------------------------------------
// Kernel B: persistent GRU recurrence. 256 blocks = 2 GRUs x 128 chunks of
// FOUR batch columns -> 1 block/CU. Block: 512 threads (8 waves). Wave w
// owns hidden units j in [16w,16w+16): resident pre-scaled W_hh A-frags.
// Per step: 12 mfma_f32_16x16x32_bf16 per wave (B cols 4..15 broadcast-alias
// cols 0..3); b_hn*N2L2E folded into the n-gate MFMA C-init; C repacked via
// scr[t][n][j] (j-stride 136 -> 2-way banks = free) with THREE masked
// ds_write_b128 + three b32 reads (R5's 12 b32 writes were the LDS-pipe
// wall); gate math 1 elem/lane with pre-scaled exp2 args; h fp32 in regs;
// h^T bf16 via 2x1KB double-buffered LDS; lgkm-only barrier.
// ---------------------------------------------------------------------------
__global__ __launch_bounds__(512) void gru_kernel(
    const int* __restrict__ x1, const int* __restrict__ x2,
    const unsigned short* __restrict__ gxv, const float* __restrict__ W_hh,
    const float* __restrict__ b_hh, float* __restrict__ fcin) {
  const int bid   = blockIdx.x;
  const int gru   = bid >> 7;         // 0..1
  const int chunk = bid & 127;        // 0..127
  const int* xs   = gru ? x2 : x1;

  const int tid = threadIdx.x;
  const int w  = tid >> 6;            // wave 0..7
  const int L  = tid & 63;            // lane
  const int q  = L >> 4;              // C-layout quad
  const int ln = L & 15;              // C-layout col (valid cols ln<4)
  const int jb = w * 16;
  const int jl = L >> 2, n = L & 3;   // repack: this lane owns (j, n)
  const int j  = jb + jl;
  const int ng = chunk * 4 + n;       // global batch index

  __shared__ __align__(16) unsigned short hbuf[2][512]; // h^T packed B-frags
  __shared__ __align__(16) float scr[3][4][136];        // repack [gate][n][j]

  // --- resident A fragments (pre-scaled): A[m=ln][k=q*8+i] per 16x16x32 ---
  short8 afrag[3][4];
#pragma unroll
  for (int t = 0; t < 3; ++t) {
    const float sc = (t < 2) ? NL2E : N2L2E;
    const float* wr = W_hh + (size_t)(t * 128 + jb + ln) * HID;
#pragma unroll
    for (int kf = 0; kf < 4; ++kf) {
      const int k0 = kf * 32 + q * 8;
      float4v f0 = *(const float4v*)(wr + k0);
      float4v f1 = *(const float4v*)(wr + k0 + 4);
      short8 a;
#pragma unroll
      for (int i = 0; i < 4; ++i) a[i] = (short)f2bf(f0[i] * sc);
#pragma unroll
      for (int i = 0; i < 4; ++i) a[i + 4] = (short)f2bf(f1[i] * sc);
      afrag[t][kf] = a;
    }
  }

  // n-gate C-init: bhn * N2L2E per C row (j = jb + q*4 + r)
  float4v bhn4;
#pragma unroll
  for (int r = 0; r < 4; ++r) bhn4[r] = N2L2E * b_hh[2 * 128 + jb + q * 4 + r];

  // zero both h buffers (h0 = 0)
  for (int idx = tid; idx < 1024; idx += 512) ((unsigned short*)hbuf)[idx] = 0;

  float h = 0.f;

  // gx prefetch: tokens two ahead, gx one ahead (3 bf16 scalars per lane)
  const int tok0 = xs[ng];
  unsigned short gxr, gxz, gxnn;
  {
    const unsigned short* gp = gxv + (size_t)tok0 * G3;
    gxr = gp[j]; gxz = gp[128 + j]; gxnn = gp[256 + j];
  }
  int tok1 = xs[BATCH + ng];

  // h' write offset in packed B-frag order: ((j>>3)*4 + n)*8 + (j&7)
  const int wofs = (((j >> 3) * 4 + n) << 3) + (j & 7);
  // B-frag read offset: cols >=4 alias col&3 (LDS same-address broadcast)
  const int rofs = ((q * 4 + (ln & 3)) << 3);

  __syncthreads();

  for (int s = 0; s < S_LEN; ++s) {
    // next-step gx gather (stays in flight across the lgkm-only barrier)
    unsigned short pr, pz, pn;
    {
      const unsigned short* gp = gxv + (size_t)tok1 * G3;
      pr = gp[j]; pz = gp[128 + j]; pn = gp[256 + j];
    }
    const int s2 = (s + 2 < S_LEN) ? (s + 2) : 0;   // uniform clamp, branchless
    const int tok2 = xs[s2 * BATCH + ng];

    // B fragments from packed h^T buffer
    const unsigned short* rb = hbuf[s & 1];
    short8 bfrag[4];
#pragma unroll
    for (int kf = 0; kf < 4; ++kf)
      bfrag[kf] = *(const short8*)(rb + kf * 128 + rofs);

    // 2 independent 2-deep MFMA chains per gate; n-gate C-init = scaled bhn
    float4v acc[3];
#pragma unroll
    for (int t = 0; t < 3; ++t) {
      float4v a0 = (t == 2) ? bhn4 : (float4v){0.f, 0.f, 0.f, 0.f};
      float4v a1 = {0.f, 0.f, 0.f, 0.f};
      a0 = __builtin_amdgcn_mfma_f32_16x16x32_bf16(afrag[t][0], bfrag[0], a0, 0, 0, 0);
      a1 = __builtin_amdgcn_mfma_f32_16x16x32_bf16(afrag[t][1], bfrag[1], a1, 0, 0, 0);
      a0 = __builtin_amdgcn_mfma_f32_16x16x32_bf16(afrag[t][2], bfrag[2], a0, 0, 0, 0);
      a1 = __builtin_amdgcn_mfma_f32_16x16x32_bf16(afrag[t][3], bfrag[3], a1, 0, 0, 0);
      acc[t] = a0 + a1;
    }

    // repack: 4 r-values contiguous in j -> one masked b128 write per gate
    if (ln < 4) {
#pragma unroll
      for (int t = 0; t < 3; ++t)
        *(float4v*)(&scr[t][ln][jb + q * 4]) = acc[t];
    }
    // wave-private RAW: compiler inserts lgkmcnt wait; no barrier needed
    const float aR = scr[0][n][j];
    const float aZ = scr[1][n][j];
    const float aN = scr[2][n][j];

    // gate math (args pre-scaled by -log2e / -2log2e): 1 elem per lane
    const float gr = bf2f(gxr) + aR;
    const float gz = bf2f(gxz) + aZ;
    const float rg = __builtin_amdgcn_rcpf(1.f + __builtin_amdgcn_exp2f(gr));
    const float zg = __builtin_amdgcn_rcpf(1.f + __builtin_amdgcn_exp2f(gz));
    const float pre = bf2f(gxnn) + rg * aN;          // already *N2L2E
    const float sg  = __builtin_amdgcn_rcpf(1.f + __builtin_amdgcn_exp2f(pre));
    const float nn  = 2.f * sg - 1.f;                // tanh
    h = zg * (h - nn) + nn;

    // write h' as bf16 (round-half-up)
    hbuf[(s + 1) & 1][wofs] = (unsigned short)((fbits(h) + 0x8000u) >> 16);

    // LDS-only barrier: do NOT drain vmcnt — gx prefetch stays in flight
    asm volatile("s_waitcnt lgkmcnt(0)\n\ts_barrier" ::: "memory");

    gxr = pr; gxz = pz; gxnn = pn;
    tok1 = tok2;
  }

  // final h -> fcin[b][gru*128 + j]
  fcin[(size_t)ng * 256 + gru * 128 + j] = h;
}

// ---------------------------------------------------------------------------
// Kernel C: out[b] = sigmoid(b2 + W2 . relu(b1 + W1 . fcin[b]))
// ---------------------------------------------------------------------------
__global__ __launch_bounds__(128) void head_kernel(
    const float* __restrict__ fcin, const float* __restrict__ W1,
    const float* __restrict__ b1, const float* __restrict__ W2,
    const float* __restrict__ b2, float* __restrict__ out) {
  __shared__ float fc[256];
  __shared__ float part[2];
  const int b = blockIdx.x, t = threadIdx.x;
  fc[t]       = fcin[(size_t)b * 256 + t];
  fc[t + 128] = fcin[(size_t)b * 256 + t + 128];
  __syncthreads();

  float acc = b1[t];
#pragma unroll 8
  for (int k = 0; k < 256; ++k) acc += W1[t * 256 + k] * fc[k];
  const float hid = fmaxf(acc, 0.f);

  float v = hid * W2[t];
#pragma unroll
  for (int o = 32; o > 0; o >>= 1) v += __shfl_xor(v, o, 64);
  if ((t & 63) == 0) part[t >> 6] = v;
  __syncthreads();
  if (t == 0) {
    const float s = part[0] + part[1] + b2[0];
    out[b] = fast_sig(s);
  }
}

// ---------------------------------------------------------------------------
extern "C" void kernel_launch(void* const* d_in, const int* in_sizes, int n_in,
                              void* d_out, int out_size, void* d_ws, size_t ws_size,
                              hipStream_t stream) {
  const int*   x1   = (const int*)d_in[0];
  const int*   x2   = (const int*)d_in[1];
  const float* emb  = (const float*)d_in[2];
  const float* W_ih = (const float*)d_in[3];
  const float* W_hh = (const float*)d_in[4];
  const float* b_ih = (const float*)d_in[5];
  const float* b_hh = (const float*)d_in[6];
  const float* W1   = (const float*)d_in[7];
  const float* b1   = (const float*)d_in[8];
  const float* W2   = (const float*)d_in[9];
  const float* b2   = (const float*)d_in[10];
  float* out = (float*)d_out;

  unsigned short* gxv = (unsigned short*)d_ws;                  // 50000*384*2 = 38.4 MB
  float* fcin = (float*)((char*)d_ws + (size_t)VOC * G3 * 2);   // 512*256*4 = 512 KB

  build_gxv<<<(VOC + 63) / 64, 256, 0, stream>>>(emb, W_ih, b_ih, b_hh, gxv);
  gru_kernel<<<256, 512, 0, stream>>>(x1, x2, gxv, W_hh, b_hh, fcin);
  head_kernel<<<512, 128, 0, stream>>>(fcin, W1, b1, W2, b2, out);
}

// Round 7
// 346.654 us; speedup vs baseline: 2.1043x; 1.1740x over previous
//
#include <hip/hip_runtime.h>
#include <hip/hip_bf16.h>
#include <stdint.h>

#define S_LEN 512
#define BATCH 512
#define HID   128
#define G3    384
#define EMB   50
#define VOC   50000

// sigmoid(x) = rcp(1 + exp2(x * -log2(e))); tanh(y) = 2*sigmoid(2y)-1.
// W_hh/gxv rows are PRE-SCALED: r,z rows by NL2E, n rows by N2L2E, so the
// gate math needs no multiplies before exp2.
#define NL2E  (-1.4426950408889634f)
#define N2L2E (-2.8853900817779268f)

typedef __attribute__((ext_vector_type(8))) short short8;
typedef __attribute__((ext_vector_type(4))) float float4v;

__device__ inline unsigned short f2bf(float f) {
  union { float f; uint32_t u; } v; v.f = f;
  uint32_t u = v.u;
  u += 0x7fffu + ((u >> 16) & 1u);   // RNE
  return (unsigned short)(u >> 16);
}
__device__ inline float bf2f(unsigned short h) {
  union { uint32_t u; float f; } v; v.u = ((uint32_t)h) << 16;
  return v.f;
}
__device__ inline uint32_t fbits(float f) {
  union { float f; uint32_t u; } v; v.f = f; return v.u;
}
__device__ inline float fast_sig(float x) {
  return __builtin_amdgcn_rcpf(1.f + __expf(-x));
}

// ---------------------------------------------------------------------------
// Kernel A0 (runs once, tiny): pre-convert W_ih to scaled bf16 B-fragments
// (B[k=q*8+i][col=ln] per 16x16x32, K zero-padded to 64) + scaled biases.
// Layout: wbf[((nt*2+kf)*64 + lane)*8 + i]; removes all f2bf VALU from
// build_gxv's 24-iter loop.
// ---------------------------------------------------------------------------
__global__ __launch_bounds__(128) void prep_wih(
    const float* __restrict__ W_ih, const float* __restrict__ b_ih,
    const float* __restrict__ b_hh, unsigned short* __restrict__ wbf,
    float* __restrict__ sbias) {
  const int nt = blockIdx.x;          // 0..23
  const int kf = threadIdx.x >> 6;    // 0..1
  const int L  = threadIdx.x & 63;
  const int q = L >> 4, ln = L & 15;
  const int g = nt * 16 + ln;
  const float sc = (g < 256) ? NL2E : N2L2E;
  const int k0 = kf * 32 + q * 8;
  short8 v;
#pragma unroll
  for (int i = 0; i < 8; ++i) {
    const int k = k0 + i;
    v[i] = (k < EMB) ? (short)f2bf(W_ih[(size_t)g * EMB + k] * sc) : (short)0;
  }
  *(short8*)(wbf + (size_t)((nt * 2 + kf) * 64 + L) * 8) = v;
  if (threadIdx.x < 16) {
    const int gg = nt * 16 + threadIdx.x;
    const float s2 = (gg < 256) ? NL2E : N2L2E;
    sbias[gg] = s2 * (b_ih[gg] + (gg < 256 ? b_hh[gg] : 0.f));
  }
}

// ---------------------------------------------------------------------------
// Kernel A (MFMA): gxv[v][g] = sc(g) * (b_ih[g] + (g<256 ? b_hh[g] : 0)
//                              + sum_e W_ih[g][e] * emb[v][e])
// v4: B-fragments pre-converted by prep_wih (2 hot b128 loads + 2 MFMA per
// iter); C staged in LDS then bulk-stored coalesced.
// ---------------------------------------------------------------------------
__global__ __launch_bounds__(256) void build_gxv(
    const float* __restrict__ emb, const unsigned short* __restrict__ wbf,
    const float* __restrict__ sbias, unsigned short* __restrict__ gxv) {
  __shared__ __align__(16) unsigned short cmat[64][392];  // 64 vocab rows, +8 pad
  const int w  = threadIdx.x >> 6;
  const int L  = threadIdx.x & 63;
  const int q  = L >> 4;
  const int ln = L & 15;
  const int vbase = blockIdx.x * 64 + w * 16;
  const int vloc  = w * 16;

  // A fragments: A[m=ln][k=q*8+i] = emb[vbase+ln][k], k zero-padded to 64
  const int vr = min(vbase + ln, VOC - 1);
  const float* arow = emb + (size_t)vr * EMB;
  float fa[16];
#pragma unroll
  for (int i = 0; i < 16; ++i) {
    const int k = ((i < 8) ? q * 8 : 32 + q * 8 - 8) + i;  // q*8+i / 32+q*8+(i-8)
    fa[i] = 0.f;
  }
  // (re-do cleanly below)
  short8 afr0, afr1;
  {
    float f[8];
#pragma unroll
    for (int i = 0; i < 8; ++i) { const int k = q * 8 + i; f[i] = (k < EMB) ? arow[k] : 0.f; }
#pragma unroll
    for (int i = 0; i < 8; ++i) afr0[i] = (short)f2bf(f[i]);
#pragma unroll
    for (int i = 0; i < 8; ++i) { const int k = 32 + q * 8 + i; f[i] = (k < EMB) ? arow[k] : 0.f; }
#pragma unroll
    for (int i = 0; i < 8; ++i) afr1[i] = (short)f2bf(f[i]);
  }

  for (int nt = 0; nt < 24; ++nt) {
    const short8 b0 = *(const short8*)(wbf + (size_t)((nt * 2 + 0) * 64 + L) * 8);
    const short8 b1 = *(const short8*)(wbf + (size_t)((nt * 2 + 1) * 64 + L) * 8);
    const int gg = nt * 16 + ln;
    const float bias = sbias[gg];
    float4v acc = {bias, bias, bias, bias};
    acc = __builtin_amdgcn_mfma_f32_16x16x32_bf16(afr0, b0, acc, 0, 0, 0);
    acc = __builtin_amdgcn_mfma_f32_16x16x32_bf16(afr1, b1, acc, 0, 0, 0);
    // C: col = ln (gate), row = q*4 + r (vocab-in-tile) -> stage in LDS
#pragma unroll
    for (int r = 0; r < 4; ++r)
      cmat[vloc + q * 4 + r][gg] = f2bf(acc[r]);
  }
  __syncthreads();

  // coalesced bulk store: 64 rows x 384 ushorts = 3072 chunks of 16B
  for (int idx = threadIdx.x; idx < 3072; idx += 256) {
    const int row = idx / 48, c8 = idx - row * 48;
    const int vrow = blockIdx.x * 64 + row;
    if (vrow < VOC) {
      short8 v = *(const short8*)(&cmat[row][c8 * 8]);
      *(short8*)(gxv + (size_t)vrow * G3 + c8 * 8) = v;
    }
  }
}

// ---------------------------------------------------------------------------
// Kernel B: persistent GRU recurrence. 256 blocks = 2 GRUs x 128 chunks of
// FOUR batch columns -> 1 block/CU. Block: 512 threads (8 waves). Wave w
// owns hidden units j in [16w,16w+16): resident pre-scaled W_hh A-frags.
// Per step: 12 mfma_f32_16x16x32_bf16 per wave; B cols 4..15 broadcast-alias
// cols 0..3, so C fragments are 4x REDUNDANT across ln-groups -> lane group
// g3=ln>>2 selects C register r=g3 via 3 cndmask (NO LDS repack round-trip
// on the critical path — R5/R6's scr scratch removed). Each lane then owns
// exactly one gate element (j = jb+q*4+g3, n = ln&3): 6 transcendentals.
// h' written with a single ds_write_b16 (64 lanes, 2-way banks = free) into
// the 2x1KB double-buffered packed-B-frag h^T buffer; lgkm-only barrier;
// depth-2 gx prefetch covers ~900cyc HBM gather latency at ~1000cyc steps.
// ---------------------------------------------------------------------------
__global__ __launch_bounds__(512) void gru_kernel(
    const int* __restrict__ x1, const int* __restrict__ x2,
    const unsigned short* __restrict__ gxv, const float* __restrict__ W_hh,
    const float* __restrict__ b_hh, float* __restrict__ fcin) {
  const int bid   = blockIdx.x;
  const int gru   = bid >> 7;         // 0..1
  const int chunk = bid & 127;        // 0..127
  const int* xs   = gru ? x2 : x1;

  const int tid = threadIdx.x;
  const int w  = tid >> 6;            // wave 0..7
  const int L  = tid & 63;            // lane
  const int q  = L >> 4;              // C-layout quad
  const int ln = L & 15;              // C-layout col group
  const int jb = w * 16;
  const int g3 = ln >> 2;             // which C register this lane consumes
  const int n  = ln & 3;              // batch column (0..3)
  const int j  = jb + q * 4 + g3;     // this lane's hidden unit
  const int ng = chunk * 4 + n;       // global batch index

  __shared__ __align__(16) unsigned short hbuf[2][512]; // h^T packed B-frags

  // --- resident A fragments (pre-scaled): A[m=ln][k=q*8+i] per 16x16x32 ---
  short8 afrag[3][4];
#pragma unroll
  for (int t = 0; t < 3; ++t) {
    const float sc = (t < 2) ? NL2E : N2L2E;
    const float* wr = W_hh + (size_t)(t * 128 + jb + ln) * HID;
#pragma unroll
    for (int kf = 0; kf < 4; ++kf) {
      const int k0 = kf * 32 + q * 8;
      float4v f0 = *(const float4v*)(wr + k0);
      float4v f1 = *(const float4v*)(wr + k0 + 4);
      short8 a;
#pragma unroll
      for (int i = 0; i < 4; ++i) a[i] = (short)f2bf(f0[i] * sc);
#pragma unroll
      for (int i = 0; i < 4; ++i) a[i + 4] = (short)f2bf(f1[i] * sc);
      afrag[t][kf] = a;
    }
  }

  // n-gate C-init: bhn * N2L2E per C row (row r -> j = jb + q*4 + r)
  float4v bhn4;
#pragma unroll
  for (int r = 0; r < 4; ++r) bhn4[r] = N2L2E * b_hh[2 * 128 + jb + q * 4 + r];

  // zero both h buffers (h0 = 0)
  for (int idx = tid; idx < 1024; idx += 512) ((unsigned short*)hbuf)[idx] = 0;

  float h = 0.f;

  // gx prefetch, depth 2: gxc for step s, gxn for s+1; each iter issues s+2.
  unsigned short gxr, gxz, gxnn, nr, nz, nn2;
  {
    const unsigned short* gp = gxv + (size_t)xs[ng] * G3;
    gxr = gp[j]; gxz = gp[128 + j]; gxnn = gp[256 + j];
    const unsigned short* gq = gxv + (size_t)xs[BATCH + ng] * G3;
    nr = gq[j]; nz = gq[128 + j]; nn2 = gq[256 + j];
  }
  int tokf = xs[2 * BATCH + ng];      // token for s+2

  // h' write offset in packed B-frag order: ((j>>3)*4 + n)*8 + (j&7)
  const int wofs = (((j >> 3) * 4 + n) << 3) + (j & 7);
  // B-frag read offset: cols >=4 alias col&3 (LDS same-address broadcast)
  const int rofs = ((q * 4 + n) << 3);

  const bool selA = (ln & 4) != 0;    // g3 bit 0
  const bool selB = (ln & 8) != 0;    // g3 bit 1

  __syncthreads();

  for (int s = 0; s < S_LEN; ++s) {
    // issue gx for step s+2 (stays in flight across two lgkm-only barriers)
    unsigned short fr, fz, fn;
    {
      const unsigned short* gp = gxv + (size_t)tokf * G3;
      fr = gp[j]; fz = gp[128 + j]; fn = gp[256 + j];
    }
    const int s3 = (s + 3 < S_LEN) ? (s + 3) : 0;   // uniform clamp, branchless
    const int tok3 = xs[s3 * BATCH + ng];

    // B fragments from packed h^T buffer
    const unsigned short* rb = hbuf[s & 1];
    short8 bfrag[4];
#pragma unroll
    for (int kf = 0; kf < 4; ++kf)
      bfrag[kf] = *(const short8*)(rb + kf * 128 + rofs);

    // 2 independent 2-deep MFMA chains per gate; n-gate C-init = scaled bhn
    float vsel[3];
#pragma unroll
    for (int t = 0; t < 3; ++t) {
      float4v a0 = (t == 2) ? bhn4 : (float4v){0.f, 0.f, 0.f, 0.f};
      float4v a1 = {0.f, 0.f, 0.f, 0.f};
      a0 = __builtin_amdgcn_mfma_f32_16x16x32_bf16(afrag[t][0], bfrag[0], a0, 0, 0, 0);
      a1 = __builtin_amdgcn_mfma_f32_16x16x32_bf16(afrag[t][1], bfrag[1], a1, 0, 0, 0);
      a0 = __builtin_amdgcn_mfma_f32_16x16x32_bf16(afrag[t][2], bfrag[2], a0, 0, 0, 0);
      a1 = __builtin_amdgcn_mfma_f32_16x16x32_bf16(afrag[t][3], bfrag[3], a1, 0, 0, 0);
      const float4v acc = a0 + a1;
      // per-lane register select: r = g3 (C redundancy across ln-groups)
      const float x0 = selA ? acc[1] : acc[0];
      const float x1 = selA ? acc[3] : acc[2];
      vsel[t] = selB ? x1 : x0;
    }

    // gate math (args pre-scaled by -log2e / -2log2e): 1 elem per lane
    const float gr = bf2f(gxr) + vsel[0];
    const float gz = bf2f(gxz) + vsel[1];
    const float rg = __builtin_amdgcn_rcpf(1.f + __builtin_amdgcn_exp2f(gr));
    const float zg = __builtin_amdgcn_rcpf(1.f + __builtin_amdgcn_exp2f(gz));
    const float pre = bf2f(gxnn) + rg * vsel[2];     // already *N2L2E
    const float sg  = __builtin_amdgcn_rcpf(1.f + __builtin_amdgcn_exp2f(pre));
    const float nn  = 2.f * sg - 1.f;                // tanh
    h = zg * (h - nn) + nn;

    // write h' as bf16 (round-half-up): one b16 write, all 64 lanes
    hbuf[(s + 1) & 1][wofs] = (unsigned short)((fbits(h) + 0x8000u) >> 16);

    // LDS-only barrier: do NOT drain vmcnt — gx prefetches stay in flight
    asm volatile("s_waitcnt lgkmcnt(0)\n\ts_barrier" ::: "memory");

    gxr = nr; gxz = nz; gxnn = nn2;
    nr = fr; nz = fz; nn2 = fn;
    tokf = tok3;
  }

  // final h -> fcin[b][gru*128 + j]
  fcin[(size_t)ng * 256 + gru * 128 + j] = h;
}

// ---------------------------------------------------------------------------
// Kernel C: out[b] = sigmoid(b2 + W2 . relu(b1 + W1 . fcin[b]))
// ---------------------------------------------------------------------------
__global__ __launch_bounds__(128) void head_kernel(
    const float* __restrict__ fcin, const float* __restrict__ W1,
    const float* __restrict__ b1, const float* __restrict__ W2,
    const float* __restrict__ b2, float* __restrict__ out) {
  __shared__ float fc[256];
  __shared__ float part[2];
  const int b = blockIdx.x, t = threadIdx.x;
  fc[t]       = fcin[(size_t)b * 256 + t];
  fc[t + 128] = fcin[(size_t)b * 256 + t + 128];
  __syncthreads();

  float acc = b1[t];
#pragma unroll 8
  for (int k = 0; k < 256; ++k) acc += W1[t * 256 + k] * fc[k];
  const float hid = fmaxf(acc, 0.f);

  float v = hid * W2[t];
#pragma unroll
  for (int o = 32; o > 0; o >>= 1) v += __shfl_xor(v, o, 64);
  if ((t & 63) == 0) part[t >> 6] = v;
  __syncthreads();
  if (t == 0) {
    const float s = part[0] + part[1] + b2[0];
    out[b] = fast_sig(s);
  }
}

// ---------------------------------------------------------------------------
extern "C" void kernel_launch(void* const* d_in, const int* in_sizes, int n_in,
                              void* d_out, int out_size, void* d_ws, size_t ws_size,
                              hipStream_t stream) {
  const int*   x1   = (const int*)d_in[0];
  const int*   x2   = (const int*)d_in[1];
  const float* emb  = (const float*)d_in[2];
  const float* W_ih = (const float*)d_in[3];
  const float* W_hh = (const float*)d_in[4];
  const float* b_ih = (const float*)d_in[5];
  const float* b_hh = (const float*)d_in[6];
  const float* W1   = (const float*)d_in[7];
  const float* b1   = (const float*)d_in[8];
  const float* W2   = (const float*)d_in[9];
  const float* b2   = (const float*)d_in[10];
  float* out = (float*)d_out;

  char* ws = (char*)d_ws;
  unsigned short* gxv = (unsigned short*)ws;                    // 38.4 MB
  float* fcin = (float*)(ws + (size_t)VOC * G3 * 2);            // 512 KB
  unsigned short* wbf = (unsigned short*)(ws + (size_t)VOC * G3 * 2 + 524288); // 48 KB
  float* sbias = (float*)(ws + (size_t)VOC * G3 * 2 + 524288 + 49152);         // 1.5 KB

  prep_wih<<<24, 128, 0, stream>>>(W_ih, b_ih, b_hh, wbf, sbias);
  build_gxv<<<(VOC + 63) / 64, 256, 0, stream>>>(emb, wbf, sbias, gxv);
  gru_kernel<<<256, 512, 0, stream>>>(x1, x2, gxv, W_hh, b_hh, fcin);
  head_kernel<<<512, 128, 0, stream>>>(fcin, W1, b1, W2, b2, out);
}